// Round 10
// baseline (508.780 us; speedup 1.0000x reference)
//
#include <hip/hip_runtime.h>

#define NN 50000
#define NE 800000
#define D_IN 128
#define D_H 256
#define D_OUT 64
#define NG 64

typedef _Float16 f16;
typedef _Float16 f16x8 __attribute__((ext_vector_type(8)));
typedef _Float16 f16x2 __attribute__((ext_vector_type(2)));
typedef unsigned short u16x8 __attribute__((ext_vector_type(8)));
typedef float f32x4 __attribute__((ext_vector_type(4)));

__device__ __forceinline__ float lrelu(float x){ return x > 0.f ? x : 0.2f*x; }

__device__ __forceinline__ unsigned short f2h(float f){
  f16 h = (f16)f;
  return __builtin_bit_cast(unsigned short, h);
}
__device__ __forceinline__ float h2f(unsigned short b){
  return (float)__builtin_bit_cast(f16, b);
}

// acc += h * w  (4x v_pk_fma_f16)
__device__ __forceinline__ void pkfma(f16x8& acc, u16x8 hraw, f16x2 w2){
  f16x8 hv = __builtin_bit_cast(f16x8, hraw);
  f16x2* a2 = (f16x2*)&acc;
  const f16x2* h2p = (const f16x2*)&hv;
  #pragma unroll
  for (int k = 0; k < 4; k++) a2[k] += h2p[k] * w2;
}

// ---- W [K][256] -> Wt packed in MFMA B-fragment order ----
__device__ __forceinline__ void cast_one_wt(const float* W, unsigned short* Wt, int K, int idx){
  int k = idx >> 8, n = idx & 255;
  int grp = (n >> 4)*(K >> 5) + (k >> 5);
  int within = ((((k >> 3) & 3) << 4) | (n & 15)) * 8 + (k & 7);
  Wt[grp*512 + within] = f2h(W[idx]);
}

// blocks 0..639: cast W1/W2/W3 | 640..642: wv vectors | 643..838: zero deg
__global__ __launch_bounds__(256) void cast_wt_all(const float* __restrict__ W1,
                                                   const float* __restrict__ W2,
                                                   const float* __restrict__ W3,
                                                   const float* __restrict__ as1,
                                                   const float* __restrict__ ad1,
                                                   const float* __restrict__ as2,
                                                   const float* __restrict__ ad2,
                                                   const float* __restrict__ as3,
                                                   const float* __restrict__ ad3,
                                                   unsigned short* __restrict__ Wt0,
                                                   unsigned short* __restrict__ Wt1,
                                                   unsigned short* __restrict__ Wt2,
                                                   float* __restrict__ wv,
                                                   int* __restrict__ deg){
  int b = blockIdx.x, t = threadIdx.x;
  if (b < 640){
    int e = b*256 + t;
    if (e < 32768)        cast_one_wt(W1, Wt0, 128, e);
    else if (e < 98304)   cast_one_wt(W2, Wt1, 256, e - 32768);
    else                  cast_one_wt(W3, Wt2, 256, e - 98304);
  } else if (b < 643){
    int L = b - 640;
    const float* W  = (L==0) ? W1 : ((L==1) ? W2 : W3);
    const float* av = (L==0) ? as1 : ((L==1) ? as2 : as3);
    const float* dv = (L==0) ? ad1 : ((L==1) ? ad2 : ad3);
    int K   = (L==0) ? 128 : 256;
    int off = (L==0) ? 0 : ((L==1) ? 256 : 768);
    int k = t;
    if (k < K){
      float ps = 0.f, pd = 0.f;
      for (int n = 0; n < 256; n += 4){
        float4 w  = *(const float4*)(W + k*256 + n);
        float4 a  = *(const float4*)(av + n);
        float4 d2 = *(const float4*)(dv + n);
        ps += w.x*a.x + w.y*a.y + w.z*a.z + w.w*a.w;
        pd += w.x*d2.x + w.y*d2.y + w.z*d2.z + w.w*d2.w;
      }
      wv[off + k]     = ps;
      wv[off + K + k] = pd;
    }
  } else {
    int i = (b - 643)*256 + t;
    if (i < NN) deg[i] = 0;
  }
}

// ---- prep: cast x to f16 + s1/d1 + degree count ----
__global__ __launch_bounds__(256) void prep_kernel(const float* __restrict__ x,
                                                   unsigned short* __restrict__ xb,
                                                   const float* __restrict__ wv,
                                                   float* __restrict__ s,
                                                   float* __restrict__ d,
                                                   const int* __restrict__ dst,
                                                   int* __restrict__ deg){
  int gid = blockIdx.x*256 + threadIdx.x;
  if (gid < NN*32){
    float4 v = ((const float4*)x)[gid];
    ushort4 o = { f2h(v.x), f2h(v.y), f2h(v.z), f2h(v.w) };
    ((ushort4*)xb)[gid] = o;
    int node = gid >> 5, sub = gid & 31;
    float4 ws = ((const float4*)wv)[sub];
    float4 wd = ((const float4*)(wv + 128))[sub];
    float ps = v.x*ws.x + v.y*ws.y + v.z*ws.z + v.w*ws.w;
    float pd = v.x*wd.x + v.y*wd.y + v.z*wd.z + v.w*wd.w;
    #pragma unroll
    for (int o2 = 16; o2 > 0; o2 >>= 1){
      ps += __shfl_down(ps, o2, 32);
      pd += __shfl_down(pd, o2, 32);
    }
    if (sub == 0){ s[node] = ps; d[node] = pd; }
  }
  if (gid < NE) atomicAdd(&deg[dst[gid]], 1);
}

// ---- CSR build ----
__global__ __launch_bounds__(256) void scan_bsum(const int* __restrict__ deg,
                                                 int* __restrict__ bsum){
  __shared__ int sm[256];
  int b = blockIdx.x, t = threadIdx.x;
  int gid = b*256 + t;
  sm[t] = (gid < NN) ? deg[gid] : 0;
  __syncthreads();
  for (int off = 128; off > 0; off >>= 1){
    if (t < off) sm[t] += sm[t+off];
    __syncthreads();
  }
  if (t == 0) bsum[b] = sm[0];
}

__global__ __launch_bounds__(256) void scan_offs(const int* __restrict__ deg,
                                                 const int* __restrict__ bsum,
                                                 int* __restrict__ offs,
                                                 int* __restrict__ cursor,
                                                 int nblk){
  __shared__ int sb[256];
  __shared__ int sm[256];
  int b = blockIdx.x, t = threadIdx.x;
  sb[t] = (t < nblk) ? bsum[t] : 0;
  __syncthreads();
  for (int off = 1; off < 256; off <<= 1){
    int v = (t >= off) ? sb[t-off] : 0;
    __syncthreads();
    sb[t] += v;
    __syncthreads();
  }
  int base = (b == 0) ? 0 : sb[b-1];
  int gid = b*256 + t;
  int v = (gid < NN) ? deg[gid] : 0;
  sm[t] = v;
  __syncthreads();
  for (int off = 1; off < 256; off <<= 1){
    int u = (t >= off) ? sm[t-off] : 0;
    __syncthreads();
    sm[t] += u;
    __syncthreads();
  }
  int incl = sm[t], excl = incl - v;
  if (gid < NN){ offs[gid] = base + excl; cursor[gid] = base + excl; }
  if (gid == NN-1) offs[NN] = base + incl;
}

__global__ void scatter_csr(const int* __restrict__ src, const int* __restrict__ dst,
                            int* __restrict__ cursor, int* __restrict__ csr_src){
  int e = blockIdx.x*256 + threadIdx.x;
  if (e < NE){
    int dd = dst[e];
    int pos = atomicAdd(&cursor[dd], 1);
    csr_src[pos] = src[e];
  }
}

// ---- f16 MFMA GEMM: half-K staged LDS (33.8KB, 4 blocks/CU), stage-1 register prefetch ----
template<int K>
__global__ __launch_bounds__(256) void gemm_f16(const unsigned short* __restrict__ A,
                                                const unsigned short* __restrict__ Wt,
                                                unsigned short* __restrict__ C16){
  constexpr int KS   = 128;          // staged K per pass
  constexpr int NSTG = K / KS;       // 1 or 2
  __shared__ unsigned short As[128*132];   // stage: 128x128; epilogue: 128x132
  const int t = threadIdx.x;
  const int bm = blockIdx.x * 128;
  const int bn = blockIdx.y * 128;
  const int wave = t >> 6, lane = t & 63;
  const int wm = (wave >> 1) * 64, wn = (wave & 1) * 64;
  const int l15 = lane & 15, quad = lane >> 4;

  const int sc  = t & 15;            // staging chunk
  const int sr0 = t >> 4;            // staging row base (16 rows/pass)
  const int sp  = sc ^ (sr0 & 7);    // XOR-swizzled chunk

  f32x4 acc[4][4];
  #pragma unroll
  for (int i = 0; i < 4; i++)
    #pragma unroll
    for (int j = 0; j < 4; j++){
      f32x4 z = {0.f, 0.f, 0.f, 0.f};
      acc[i][j] = z;
    }

  // stage 0
  #pragma unroll
  for (int g = 0; g < 8; g++){
    int row = sr0 + g*16;
    int grow = bm + row;
    u16x8 v = {0,0,0,0,0,0,0,0};
    if (grow < NN) v = *(const u16x8*)(A + (size_t)grow*K + sc*8);
    *(u16x8*)(&As[row*128 + sp*8]) = v;
  }
  // prefetch half of stage 1 into registers (overlaps stage-0 compute)
  u16x8 pre[4];
  if (NSTG == 2){
    #pragma unroll
    for (int g = 0; g < 4; g++){
      int grow = bm + sr0 + g*16;
      u16x8 v = {0,0,0,0,0,0,0,0};
      if (grow < NN) v = *(const u16x8*)(A + (size_t)grow*K + KS + sc*8);
      pre[g] = v;
    }
  }
  __syncthreads();

  #pragma unroll
  for (int stg = 0; stg < NSTG; stg++){
    if (stg > 0){
      __syncthreads();
      #pragma unroll
      for (int g = 0; g < 4; g++)
        *(u16x8*)(&As[(sr0 + g*16)*128 + sp*8]) = pre[g];
      #pragma unroll
      for (int g = 4; g < 8; g++){
        int row = sr0 + g*16;
        int grow = bm + row;
        u16x8 v = {0,0,0,0,0,0,0,0};
        if (grow < NN) v = *(const u16x8*)(A + (size_t)grow*K + KS + sc*8);
        *(u16x8*)(&As[row*128 + sp*8]) = v;
      }
      __syncthreads();
    }
    #pragma unroll
    for (int ksl = 0; ksl < KS/32; ksl++){
      const int ks = stg*(KS/32) + ksl;
      f16x8 af[4];
      const int pc = ((ksl*4 + quad) ^ (l15 & 7)) * 8;
      #pragma unroll
      for (int i = 0; i < 4; i++)
        af[i] = *(const f16x8*)(&As[(wm + i*16 + l15)*128 + pc]);
      #pragma unroll
      for (int j = 0; j < 4; j++){
        int nb = ((bn + wn) >> 4) + j;
        f16x8 bfr = *(const f16x8*)(Wt + ((size_t)(nb*(K>>5) + ks))*512 + lane*8);
        #pragma unroll
        for (int i = 0; i < 4; i++)
          acc[i][j] = __builtin_amdgcn_mfma_f32_16x16x32_f16(af[i], bfr, acc[i][j], 0, 0, 0);
      }
    }
  }

  // epilogue: pack f16 tile into LDS (stride 132), coalesced 16B stores
  __syncthreads();
  #pragma unroll
  for (int i = 0; i < 4; i++)
    #pragma unroll
    for (int j = 0; j < 4; j++)
      #pragma unroll
      for (int r = 0; r < 4; r++)
        As[(wm + i*16 + quad*4 + r)*132 + wn + j*16 + l15] = f2h(acc[i][j][r]);
  __syncthreads();
  {
    const int rl = t >> 1, hc = (t & 1)*64;
    const int grow = bm + rl;
    if (grow < NN){
      #pragma unroll
      for (int u = 0; u < 8; u++){
        u16x8 v = *(const u16x8*)(&As[rl*132 + hc + u*8]);
        *(u16x8*)(C16 + (size_t)grow*256 + bn + hc + u*8) = v;
      }
    }
  }
}

// ---- fused softmax + aggregation + next-layer s/d (round-8 structure) ----
__global__ __launch_bounds__(256) void agg_kernel(const unsigned short* __restrict__ h16,
                                                  const int* __restrict__ offs,
                                                  const int* __restrict__ csr_src,
                                                  const float* __restrict__ s,
                                                  const float* __restrict__ d,
                                                  const float* __restrict__ bias,
                                                  unsigned short* __restrict__ hout16,
                                                  const float* __restrict__ wv_s,
                                                  const float* __restrict__ wv_d,
                                                  float* __restrict__ s_next,
                                                  float* __restrict__ d_next,
                                                  int do_sd){
  __shared__ int2 meta[4][64];
  const int wvi = threadIdx.x >> 6;
  const int node = blockIdx.x*4 + wvi;
  const int lane = threadIdx.x & 63;
  if (node >= NN) return;
  const float d_i = d[node];
  const int beg = offs[node], end = offs[node+1];
  const int deg = end - beg;

  const int half = lane >> 5;
  const int c    = lane & 31;
  const u16x8* h8 = (const u16x8*)h16;

  f16x8 acc8 = {0,0,0,0,0,0,0,0};
  float inv_den;

  if (deg <= 63){
    int sj = 0;
    float e = -1e30f;
    if (lane < deg){
      sj = csr_src[beg + lane];
      e = lrelu(s[sj] + d_i);
    }
    float m = e;
    #pragma unroll
    for (int o = 32; o > 0; o >>= 1) m = fmaxf(m, __shfl_xor(m, o));
    const float e0 = lrelu(s[node] + d_i);
    m = fmaxf(m, e0);

    float w = 0.f;
    if (lane < deg) w = __expf(e - m);
    else if (lane == deg){ w = __expf(e0 - m); sj = node; }
    float den = w;
    #pragma unroll
    for (int o = 32; o > 0; o >>= 1) den += __shfl_xor(den, o);
    inv_den = 1.f / den;

    const int np = (deg + 8) & ~7;          // slots 0..deg (+self), padded; np <= 64
    f16 wh = (f16)w;
    f16x2 wp = {wh, wh};
    if (lane < np) meta[wvi][lane] = make_int2(sj, __builtin_bit_cast(int, wp));

    for (int eb = 0; eb < np; eb += 8){
      int2 m0 = meta[wvi][eb + half];
      int2 m1 = meta[wvi][eb + 2 + half];
      int2 m2 = meta[wvi][eb + 4 + half];
      int2 m3 = meta[wvi][eb + 6 + half];
      u16x8 h0 = h8[(size_t)m0.x*32 + c];
      u16x8 h1 = h8[(size_t)m1.x*32 + c];
      u16x8 h2 = h8[(size_t)m2.x*32 + c];
      u16x8 h3 = h8[(size_t)m3.x*32 + c];
      pkfma(acc8, h0, __builtin_bit_cast(f16x2, m0.y));
      pkfma(acc8, h1, __builtin_bit_cast(f16x2, m1.y));
      pkfma(acc8, h2, __builtin_bit_cast(f16x2, m2.y));
      pkfma(acc8, h3, __builtin_bit_cast(f16x2, m3.y));
    }
  } else {
    // correctness fallback (deg > 63)
    float m_l = -1e30f;
    for (int j = lane; j < deg; j += 64){
      int sj = csr_src[beg + j];
      m_l = fmaxf(m_l, lrelu(s[sj] + d_i));
    }
    #pragma unroll
    for (int o = 32; o > 0; o >>= 1) m_l = fmaxf(m_l, __shfl_xor(m_l, o));
    const float e0 = lrelu(s[node] + d_i);
    const float m = fmaxf(m_l, e0);
    float den_l = (lane == 0) ? __expf(e0 - m) : 0.f;
    for (int j = lane; j < deg; j += 64){
      int sj = csr_src[beg + j];
      den_l += __expf(lrelu(s[sj] + d_i) - m);
    }
    #pragma unroll
    for (int o = 32; o > 0; o >>= 1) den_l += __shfl_xor(den_l, o);
    inv_den = 1.f / den_l;

    if (half == 0){
      f16 w0h = (f16)__expf(e0 - m);
      f16x2 wp0 = {w0h, w0h};
      pkfma(acc8, h8[(size_t)node*32 + c], wp0);
    }
    for (int eb = beg; eb < end; eb += 4){
      int e1 = eb + half;
      int e2 = e1 + 2;
      int sa = csr_src[min(e1, end-1)];
      int sb = csr_src[min(e2, end-1)];
      float wa = (e1 < end) ? __expf(lrelu(s[sa] + d_i) - m) : 0.f;
      float wb = (e2 < end) ? __expf(lrelu(s[sb] + d_i) - m) : 0.f;
      f16 wah = (f16)wa, wbh = (f16)wb;
      f16x2 wap = {wah, wah}, wbp = {wbh, wbh};
      pkfma(acc8, h8[(size_t)sa*32 + c], wap);
      pkfma(acc8, h8[(size_t)sb*32 + c], wbp);
    }
  }

  // f32 + normalize, merge halves
  float acc[8];
  #pragma unroll
  for (int i = 0; i < 8; i++) acc[i] = (float)acc8[i] * inv_den;
  #pragma unroll
  for (int i = 0; i < 8; i++) acc[i] += __shfl_xor(acc[i], 32);

  const float4* bb = (const float4*)(bias + c*8);
  float4 b0 = bb[0], b1 = bb[1];
  acc[0] = fmaxf(acc[0] + b0.x, 0.f); acc[1] = fmaxf(acc[1] + b0.y, 0.f);
  acc[2] = fmaxf(acc[2] + b0.z, 0.f); acc[3] = fmaxf(acc[3] + b0.w, 0.f);
  acc[4] = fmaxf(acc[4] + b1.x, 0.f); acc[5] = fmaxf(acc[5] + b1.y, 0.f);
  acc[6] = fmaxf(acc[6] + b1.z, 0.f); acc[7] = fmaxf(acc[7] + b1.w, 0.f);

  if (half == 0){
    u16x8 o;
    #pragma unroll
    for (int i = 0; i < 8; i++) o[i] = f2h(acc[i]);
    ((u16x8*)hout16)[(size_t)node*32 + c] = o;
  }

  if (do_sd){
    const float4* ws4 = (const float4*)(wv_s + c*8);
    const float4* wd4 = (const float4*)(wv_d + c*8);
    float4 s0 = ws4[0], s1 = ws4[1], dd0 = wd4[0], dd1 = wd4[1];
    float ps = acc[0]*s0.x + acc[1]*s0.y + acc[2]*s0.z + acc[3]*s0.w
             + acc[4]*s1.x + acc[5]*s1.y + acc[6]*s1.z + acc[7]*s1.w;
    float pd = acc[0]*dd0.x + acc[1]*dd0.y + acc[2]*dd0.z + acc[3]*dd0.w
             + acc[4]*dd1.x + acc[5]*dd1.y + acc[6]*dd1.z + acc[7]*dd1.w;
    #pragma unroll
    for (int o = 16; o > 0; o >>= 1){
      ps += __shfl_xor(ps, o);
      pd += __shfl_xor(pd, o);
    }
    if (lane == 0){ s_next[node] = ps; d_next[node] = pd; }
  }
}

// ---- fused global-add-pool + FC: one 1024-thread block per graph ----
__device__ __forceinline__ int lbound(const int* a, int n, int v){
  int lo = 0, hi = n;
  while (lo < hi){ int mid = (lo + hi) >> 1; if (a[mid] < v) lo = mid + 1; else hi = mid; }
  return lo;
}

__global__ __launch_bounds__(1024) void poolfc_kernel(const unsigned short* __restrict__ h16,
                                                      const int* __restrict__ batch,
                                                      const float* __restrict__ fcW,
                                                      const float* __restrict__ fcb,
                                                      float* __restrict__ out){
  __shared__ float ps[1024];
  int g = blockIdx.x, t = threadIdx.x;
  int col = t & 255, split = t >> 8;           // 4 row-splits
  int lo = lbound(batch, NN, g);
  int hi = lbound(batch, NN, g + 1);
  float acc = 0.f;
  for (int i = lo + split; i < hi; i += 4)
    acc += h2f(h16[(size_t)i*D_H + col]);
  ps[t] = acc;
  __syncthreads();
  if (t < 256) ps[t] += ps[t+256] + ps[t+512] + ps[t+768];
  __syncthreads();
  if (t < D_OUT){
    float o = fcb[t];
    for (int k = 0; k < D_H; k++) o += ps[k] * fcW[k*D_OUT + t];
    out[g*D_OUT + t] = o;
  }
}

extern "C" void kernel_launch(void* const* d_in, const int* in_sizes, int n_in,
                              void* d_out, int out_size, void* d_ws, size_t ws_size,
                              hipStream_t stream){
  const float* x     = (const float*)d_in[0];
  const int*   ei    = (const int*)d_in[1];
  const int*   batch = (const int*)d_in[2];
  const float* W1  = (const float*)d_in[3];
  const float* as1 = (const float*)d_in[4];
  const float* ad1 = (const float*)d_in[5];
  const float* b1  = (const float*)d_in[6];
  const float* W2  = (const float*)d_in[7];
  const float* as2 = (const float*)d_in[8];
  const float* ad2 = (const float*)d_in[9];
  const float* b2  = (const float*)d_in[10];
  const float* W3  = (const float*)d_in[11];
  const float* as3 = (const float*)d_in[12];
  const float* ad3 = (const float*)d_in[13];
  const float* b3  = (const float*)d_in[14];
  const float* fcW = (const float*)d_in[15];
  const float* fcb = (const float*)d_in[16];

  const int* src = ei;
  const int* dst = ei + NE;

  char* p = (char*)d_ws;
  auto alloc = [&](size_t bytes) -> void* {
    void* r = (void*)p;
    p += (bytes + 255) & ~(size_t)255;
    return r;
  };
  unsigned short* h_a16 = (unsigned short*)alloc((size_t)NN*D_H*2);
  unsigned short* h_b16 = (unsigned short*)alloc((size_t)NN*D_H*2);
  unsigned short* xb    = (unsigned short*)alloc((size_t)NN*D_IN*2);
  unsigned short* Wt0   = (unsigned short*)alloc((size_t)256*D_IN*2);
  unsigned short* Wt1   = (unsigned short*)alloc((size_t)256*256*2);
  unsigned short* Wt2   = (unsigned short*)alloc((size_t)256*256*2);
  float* sA     = (float*)alloc((size_t)NN*4);
  float* dA     = (float*)alloc((size_t)NN*4);
  float* sB     = (float*)alloc((size_t)NN*4);
  float* dB     = (float*)alloc((size_t)NN*4);
  float* wv     = (float*)alloc((size_t)1280*4);
  int* deg      = (int*)alloc((size_t)NN*4);
  int* offs     = (int*)alloc((size_t)(NN+1)*4);
  int* cursor   = (int*)alloc((size_t)NN*4);
  int* bsum     = (int*)alloc((size_t)256*4);
  int* csr      = (int*)alloc((size_t)NE*4);

  const int nblk = (NN + 255)/256;   // 196

  cast_wt_all<<<839, 256, 0, stream>>>(W1, W2, W3, as1, ad1, as2, ad2, as3, ad3,
                                       Wt0, Wt1, Wt2, wv, deg);
  prep_kernel<<<(NN*32 + 255)/256, 256, 0, stream>>>(x, xb, wv, sA, dA, dst, deg);
  scan_bsum<<<nblk, 256, 0, stream>>>(deg, bsum);
  scan_offs<<<nblk, 256, 0, stream>>>(deg, bsum, offs, cursor, nblk);
  scatter_csr<<<(NE + 255)/256, 256, 0, stream>>>(src, dst, cursor, csr);

  const int mgrid = (NN + 127)/128;
  const int agrid = (NN + 3)/4;

  gemm_f16<128><<<dim3(mgrid, 2), 256, 0, stream>>>(xb, Wt0, h_a16);
  agg_kernel<<<agrid, 256, 0, stream>>>(h_a16, offs, csr, sA, dA, b1, h_b16,
                                        wv + 256, wv + 512, sB, dB, 1);
  gemm_f16<256><<<dim3(mgrid, 2), 256, 0, stream>>>(h_b16, Wt1, h_a16);
  agg_kernel<<<agrid, 256, 0, stream>>>(h_a16, offs, csr, sB, dB, b2, h_b16,
                                        wv + 768, wv + 1024, sA, dA, 1);
  gemm_f16<256><<<dim3(mgrid, 2), 256, 0, stream>>>(h_b16, Wt2, h_a16);
  agg_kernel<<<agrid, 256, 0, stream>>>(h_a16, offs, csr, sA, dA, b3, h_b16,
                                        (const float*)nullptr, (const float*)nullptr,
                                        (float*)nullptr, (float*)nullptr, 0);

  poolfc_kernel<<<NG, 1024, 0, stream>>>(h_b16, batch, fcW, fcb, (float*)d_out);
}

// Round 11
// 476.224 us; speedup vs baseline: 1.0684x; 1.0684x over previous
//
#include <hip/hip_runtime.h>

#define NN 50000
#define NE 800000
#define D_IN 128
#define D_H 256
#define D_OUT 64
#define NG 64

typedef _Float16 f16;
typedef _Float16 f16x8 __attribute__((ext_vector_type(8)));
typedef _Float16 f16x2 __attribute__((ext_vector_type(2)));
typedef unsigned short u16x8 __attribute__((ext_vector_type(8)));
typedef float f32x4 __attribute__((ext_vector_type(4)));

__device__ __forceinline__ float lrelu(float x){ return x > 0.f ? x : 0.2f*x; }

__device__ __forceinline__ unsigned short f2h(float f){
  f16 h = (f16)f;
  return __builtin_bit_cast(unsigned short, h);
}
__device__ __forceinline__ float h2f(unsigned short b){
  return (float)__builtin_bit_cast(f16, b);
}

// acc += h * w  (4x v_pk_fma_f16)
__device__ __forceinline__ void pkfma(f16x8& acc, u16x8 hraw, f16x2 w2){
  f16x8 hv = __builtin_bit_cast(f16x8, hraw);
  f16x2* a2 = (f16x2*)&acc;
  const f16x2* h2p = (const f16x2*)&hv;
  #pragma unroll
  for (int k = 0; k < 4; k++) a2[k] += h2p[k] * w2;
}

// ---- W [K][256] -> Wt packed in MFMA B-fragment order ----
__device__ __forceinline__ void cast_one_wt(const float* W, unsigned short* Wt, int K, int idx){
  int k = idx >> 8, n = idx & 255;
  int grp = (n >> 4)*(K >> 5) + (k >> 5);
  int within = ((((k >> 3) & 3) << 4) | (n & 15)) * 8 + (k & 7);
  Wt[grp*512 + within] = f2h(W[idx]);
}

// blocks 0..639: cast W1/W2/W3 | 640..642: wv vectors | 643..838: zero deg | 839..902: zero pooled
__global__ __launch_bounds__(256) void cast_wt_all(const float* __restrict__ W1,
                                                   const float* __restrict__ W2,
                                                   const float* __restrict__ W3,
                                                   const float* __restrict__ as1,
                                                   const float* __restrict__ ad1,
                                                   const float* __restrict__ as2,
                                                   const float* __restrict__ ad2,
                                                   const float* __restrict__ as3,
                                                   const float* __restrict__ ad3,
                                                   unsigned short* __restrict__ Wt0,
                                                   unsigned short* __restrict__ Wt1,
                                                   unsigned short* __restrict__ Wt2,
                                                   float* __restrict__ wv,
                                                   int* __restrict__ deg,
                                                   float* __restrict__ pooled){
  int b = blockIdx.x, t = threadIdx.x;
  if (b < 640){
    int e = b*256 + t;
    if (e < 32768)        cast_one_wt(W1, Wt0, 128, e);
    else if (e < 98304)   cast_one_wt(W2, Wt1, 256, e - 32768);
    else                  cast_one_wt(W3, Wt2, 256, e - 98304);
  } else if (b < 643){
    int L = b - 640;
    const float* W  = (L==0) ? W1 : ((L==1) ? W2 : W3);
    const float* av = (L==0) ? as1 : ((L==1) ? as2 : as3);
    const float* dv = (L==0) ? ad1 : ((L==1) ? ad2 : ad3);
    int K   = (L==0) ? 128 : 256;
    int off = (L==0) ? 0 : ((L==1) ? 256 : 768);
    int k = t;
    if (k < K){
      float ps = 0.f, pd = 0.f;
      for (int n = 0; n < 256; n += 4){
        float4 w  = *(const float4*)(W + k*256 + n);
        float4 a  = *(const float4*)(av + n);
        float4 d2 = *(const float4*)(dv + n);
        ps += w.x*a.x + w.y*a.y + w.z*a.z + w.w*a.w;
        pd += w.x*d2.x + w.y*d2.y + w.z*d2.z + w.w*d2.w;
      }
      wv[off + k]     = ps;
      wv[off + K + k] = pd;
    }
  } else if (b < 839){
    int i = (b - 643)*256 + t;
    if (i < NN) deg[i] = 0;
  } else {
    pooled[(b - 839)*256 + t] = 0.f;
  }
}

// ---- prep: cast x to f16 + s1/d1 + degree count ----
__global__ __launch_bounds__(256) void prep_kernel(const float* __restrict__ x,
                                                   unsigned short* __restrict__ xb,
                                                   const float* __restrict__ wv,
                                                   float* __restrict__ s,
                                                   float* __restrict__ d,
                                                   const int* __restrict__ dst,
                                                   int* __restrict__ deg){
  int gid = blockIdx.x*256 + threadIdx.x;
  if (gid < NN*32){
    float4 v = ((const float4*)x)[gid];
    ushort4 o = { f2h(v.x), f2h(v.y), f2h(v.z), f2h(v.w) };
    ((ushort4*)xb)[gid] = o;
    int node = gid >> 5, sub = gid & 31;
    float4 ws = ((const float4*)wv)[sub];
    float4 wd = ((const float4*)(wv + 128))[sub];
    float ps = v.x*ws.x + v.y*ws.y + v.z*ws.z + v.w*ws.w;
    float pd = v.x*wd.x + v.y*wd.y + v.z*wd.z + v.w*wd.w;
    #pragma unroll
    for (int o2 = 16; o2 > 0; o2 >>= 1){
      ps += __shfl_down(ps, o2, 32);
      pd += __shfl_down(pd, o2, 32);
    }
    if (sub == 0){ s[node] = ps; d[node] = pd; }
  }
  if (gid < NE) atomicAdd(&deg[dst[gid]], 1);
}

// ---- CSR build ----
__global__ __launch_bounds__(256) void scan_bsum(const int* __restrict__ deg,
                                                 int* __restrict__ bsum){
  __shared__ int sm[256];
  int b = blockIdx.x, t = threadIdx.x;
  int gid = b*256 + t;
  sm[t] = (gid < NN) ? deg[gid] : 0;
  __syncthreads();
  for (int off = 128; off > 0; off >>= 1){
    if (t < off) sm[t] += sm[t+off];
    __syncthreads();
  }
  if (t == 0) bsum[b] = sm[0];
}

__global__ __launch_bounds__(256) void scan_offs(const int* __restrict__ deg,
                                                 const int* __restrict__ bsum,
                                                 int* __restrict__ offs,
                                                 int* __restrict__ cursor,
                                                 int nblk){
  __shared__ int sb[256];
  __shared__ int sm[256];
  int b = blockIdx.x, t = threadIdx.x;
  sb[t] = (t < nblk) ? bsum[t] : 0;
  __syncthreads();
  for (int off = 1; off < 256; off <<= 1){
    int v = (t >= off) ? sb[t-off] : 0;
    __syncthreads();
    sb[t] += v;
    __syncthreads();
  }
  int base = (b == 0) ? 0 : sb[b-1];
  int gid = b*256 + t;
  int v = (gid < NN) ? deg[gid] : 0;
  sm[t] = v;
  __syncthreads();
  for (int off = 1; off < 256; off <<= 1){
    int u = (t >= off) ? sm[t-off] : 0;
    __syncthreads();
    sm[t] += u;
    __syncthreads();
  }
  int incl = sm[t], excl = incl - v;
  if (gid < NN){ offs[gid] = base + excl; cursor[gid] = base + excl; }
  if (gid == NN-1) offs[NN] = base + incl;
}

__global__ void scatter_csr(const int* __restrict__ src, const int* __restrict__ dst,
                            int* __restrict__ cursor, int* __restrict__ csr_src){
  int e = blockIdx.x*256 + threadIdx.x;
  if (e < NE){
    int dd = dst[e];
    int pos = atomicAdd(&cursor[dd], 1);
    csr_src[pos] = src[e];
  }
}

// ---- f16 MFMA GEMM: half-K staged LDS (33.8KB, 4 blocks/CU), stage-1 register prefetch ----
template<int K>
__global__ __launch_bounds__(256) void gemm_f16(const unsigned short* __restrict__ A,
                                                const unsigned short* __restrict__ Wt,
                                                unsigned short* __restrict__ C16){
  constexpr int KS   = 128;          // staged K per pass
  constexpr int NSTG = K / KS;       // 1 or 2
  __shared__ unsigned short As[128*132];   // stage: 128x128; epilogue: 128x132
  const int t = threadIdx.x;
  const int bm = blockIdx.x * 128;
  const int bn = blockIdx.y * 128;
  const int wave = t >> 6, lane = t & 63;
  const int wm = (wave >> 1) * 64, wn = (wave & 1) * 64;
  const int l15 = lane & 15, quad = lane >> 4;

  const int sc  = t & 15;            // staging chunk
  const int sr0 = t >> 4;            // staging row base (16 rows/pass)
  const int sp  = sc ^ (sr0 & 7);    // XOR-swizzled chunk

  f32x4 acc[4][4];
  #pragma unroll
  for (int i = 0; i < 4; i++)
    #pragma unroll
    for (int j = 0; j < 4; j++){
      f32x4 z = {0.f, 0.f, 0.f, 0.f};
      acc[i][j] = z;
    }

  // stage 0
  #pragma unroll
  for (int g = 0; g < 8; g++){
    int row = sr0 + g*16;
    int grow = bm + row;
    u16x8 v = {0,0,0,0,0,0,0,0};
    if (grow < NN) v = *(const u16x8*)(A + (size_t)grow*K + sc*8);
    *(u16x8*)(&As[row*128 + sp*8]) = v;
  }
  // prefetch half of stage 1 into registers (overlaps stage-0 compute)
  u16x8 pre[4];
  if (NSTG == 2){
    #pragma unroll
    for (int g = 0; g < 4; g++){
      int grow = bm + sr0 + g*16;
      u16x8 v = {0,0,0,0,0,0,0,0};
      if (grow < NN) v = *(const u16x8*)(A + (size_t)grow*K + KS + sc*8);
      pre[g] = v;
    }
  }
  __syncthreads();

  #pragma unroll
  for (int stg = 0; stg < NSTG; stg++){
    if (stg > 0){
      __syncthreads();
      #pragma unroll
      for (int g = 0; g < 4; g++)
        *(u16x8*)(&As[(sr0 + g*16)*128 + sp*8]) = pre[g];
      #pragma unroll
      for (int g = 4; g < 8; g++){
        int row = sr0 + g*16;
        int grow = bm + row;
        u16x8 v = {0,0,0,0,0,0,0,0};
        if (grow < NN) v = *(const u16x8*)(A + (size_t)grow*K + KS + sc*8);
        *(u16x8*)(&As[row*128 + sp*8]) = v;
      }
      __syncthreads();
    }
    #pragma unroll
    for (int ksl = 0; ksl < KS/32; ksl++){
      const int ks = stg*(KS/32) + ksl;
      f16x8 af[4];
      const int pc = ((ksl*4 + quad) ^ (l15 & 7)) * 8;
      #pragma unroll
      for (int i = 0; i < 4; i++)
        af[i] = *(const f16x8*)(&As[(wm + i*16 + l15)*128 + pc]);
      #pragma unroll
      for (int j = 0; j < 4; j++){
        int nb = ((bn + wn) >> 4) + j;
        f16x8 bfr = *(const f16x8*)(Wt + ((size_t)(nb*(K>>5) + ks))*512 + lane*8);
        #pragma unroll
        for (int i = 0; i < 4; i++)
          acc[i][j] = __builtin_amdgcn_mfma_f32_16x16x32_f16(af[i], bfr, acc[i][j], 0, 0, 0);
      }
    }
  }

  // epilogue: pack f16 tile into LDS (stride 132), coalesced 16B stores
  __syncthreads();
  #pragma unroll
  for (int i = 0; i < 4; i++)
    #pragma unroll
    for (int j = 0; j < 4; j++)
      #pragma unroll
      for (int r = 0; r < 4; r++)
        As[(wm + i*16 + quad*4 + r)*132 + wn + j*16 + l15] = f2h(acc[i][j][r]);
  __syncthreads();
  {
    const int rl = t >> 1, hc = (t & 1)*64;
    const int grow = bm + rl;
    if (grow < NN){
      #pragma unroll
      for (int u = 0; u < 8; u++){
        u16x8 v = *(const u16x8*)(&As[rl*132 + hc + u*8]);
        *(u16x8*)(C16 + (size_t)grow*256 + bn + hc + u*8) = v;
      }
    }
  }
}

// ---- fused softmax + aggregation + next-layer s/d (round-8 structure) ----
__global__ __launch_bounds__(256) void agg_kernel(const unsigned short* __restrict__ h16,
                                                  const int* __restrict__ offs,
                                                  const int* __restrict__ csr_src,
                                                  const float* __restrict__ s,
                                                  const float* __restrict__ d,
                                                  const float* __restrict__ bias,
                                                  unsigned short* __restrict__ hout16,
                                                  const float* __restrict__ wv_s,
                                                  const float* __restrict__ wv_d,
                                                  float* __restrict__ s_next,
                                                  float* __restrict__ d_next,
                                                  int do_sd){
  __shared__ int2 meta[4][64];
  const int wvi = threadIdx.x >> 6;
  const int node = blockIdx.x*4 + wvi;
  const int lane = threadIdx.x & 63;
  if (node >= NN) return;
  const float d_i = d[node];
  const int beg = offs[node], end = offs[node+1];
  const int deg = end - beg;

  const int half = lane >> 5;
  const int c    = lane & 31;
  const u16x8* h8 = (const u16x8*)h16;

  f16x8 acc8 = {0,0,0,0,0,0,0,0};
  float inv_den;

  if (deg <= 63){
    int sj = 0;
    float e = -1e30f;
    if (lane < deg){
      sj = csr_src[beg + lane];
      e = lrelu(s[sj] + d_i);
    }
    float m = e;
    #pragma unroll
    for (int o = 32; o > 0; o >>= 1) m = fmaxf(m, __shfl_xor(m, o));
    const float e0 = lrelu(s[node] + d_i);
    m = fmaxf(m, e0);

    float w = 0.f;
    if (lane < deg) w = __expf(e - m);
    else if (lane == deg){ w = __expf(e0 - m); sj = node; }
    float den = w;
    #pragma unroll
    for (int o = 32; o > 0; o >>= 1) den += __shfl_xor(den, o);
    inv_den = 1.f / den;

    const int np = (deg + 8) & ~7;          // slots 0..deg (+self), padded; np <= 64
    f16 wh = (f16)w;
    f16x2 wp = {wh, wh};
    if (lane < np) meta[wvi][lane] = make_int2(sj, __builtin_bit_cast(int, wp));

    for (int eb = 0; eb < np; eb += 8){
      int2 m0 = meta[wvi][eb + half];
      int2 m1 = meta[wvi][eb + 2 + half];
      int2 m2 = meta[wvi][eb + 4 + half];
      int2 m3 = meta[wvi][eb + 6 + half];
      u16x8 h0 = h8[(size_t)m0.x*32 + c];
      u16x8 h1 = h8[(size_t)m1.x*32 + c];
      u16x8 h2 = h8[(size_t)m2.x*32 + c];
      u16x8 h3 = h8[(size_t)m3.x*32 + c];
      pkfma(acc8, h0, __builtin_bit_cast(f16x2, m0.y));
      pkfma(acc8, h1, __builtin_bit_cast(f16x2, m1.y));
      pkfma(acc8, h2, __builtin_bit_cast(f16x2, m2.y));
      pkfma(acc8, h3, __builtin_bit_cast(f16x2, m3.y));
    }
  } else {
    // correctness fallback (deg > 63)
    float m_l = -1e30f;
    for (int j = lane; j < deg; j += 64){
      int sj = csr_src[beg + j];
      m_l = fmaxf(m_l, lrelu(s[sj] + d_i));
    }
    #pragma unroll
    for (int o = 32; o > 0; o >>= 1) m_l = fmaxf(m_l, __shfl_xor(m_l, o));
    const float e0 = lrelu(s[node] + d_i);
    const float m = fmaxf(m_l, e0);
    float den_l = (lane == 0) ? __expf(e0 - m) : 0.f;
    for (int j = lane; j < deg; j += 64){
      int sj = csr_src[beg + j];
      den_l += __expf(lrelu(s[sj] + d_i) - m);
    }
    #pragma unroll
    for (int o = 32; o > 0; o >>= 1) den_l += __shfl_xor(den_l, o);
    inv_den = 1.f / den_l;

    if (half == 0){
      f16 w0h = (f16)__expf(e0 - m);
      f16x2 wp0 = {w0h, w0h};
      pkfma(acc8, h8[(size_t)node*32 + c], wp0);
    }
    for (int eb = beg; eb < end; eb += 4){
      int e1 = eb + half;
      int e2 = e1 + 2;
      int sa = csr_src[min(e1, end-1)];
      int sb = csr_src[min(e2, end-1)];
      float wa = (e1 < end) ? __expf(lrelu(s[sa] + d_i) - m) : 0.f;
      float wb = (e2 < end) ? __expf(lrelu(s[sb] + d_i) - m) : 0.f;
      f16 wah = (f16)wa, wbh = (f16)wb;
      f16x2 wap = {wah, wah}, wbp = {wbh, wbh};
      pkfma(acc8, h8[(size_t)sa*32 + c], wap);
      pkfma(acc8, h8[(size_t)sb*32 + c], wbp);
    }
  }

  // f32 + normalize, merge halves
  float acc[8];
  #pragma unroll
  for (int i = 0; i < 8; i++) acc[i] = (float)acc8[i] * inv_den;
  #pragma unroll
  for (int i = 0; i < 8; i++) acc[i] += __shfl_xor(acc[i], 32);

  const float4* bb = (const float4*)(bias + c*8);
  float4 b0 = bb[0], b1 = bb[1];
  acc[0] = fmaxf(acc[0] + b0.x, 0.f); acc[1] = fmaxf(acc[1] + b0.y, 0.f);
  acc[2] = fmaxf(acc[2] + b0.z, 0.f); acc[3] = fmaxf(acc[3] + b0.w, 0.f);
  acc[4] = fmaxf(acc[4] + b1.x, 0.f); acc[5] = fmaxf(acc[5] + b1.y, 0.f);
  acc[6] = fmaxf(acc[6] + b1.z, 0.f); acc[7] = fmaxf(acc[7] + b1.w, 0.f);

  if (half == 0){
    u16x8 o;
    #pragma unroll
    for (int i = 0; i < 8; i++) o[i] = f2h(acc[i]);
    ((u16x8*)hout16)[(size_t)node*32 + c] = o;
  }

  if (do_sd){
    const float4* ws4 = (const float4*)(wv_s + c*8);
    const float4* wd4 = (const float4*)(wv_d + c*8);
    float4 s0 = ws4[0], s1 = ws4[1], dd0 = wd4[0], dd1 = wd4[1];
    float ps = acc[0]*s0.x + acc[1]*s0.y + acc[2]*s0.z + acc[3]*s0.w
             + acc[4]*s1.x + acc[5]*s1.y + acc[6]*s1.z + acc[7]*s1.w;
    float pd = acc[0]*dd0.x + acc[1]*dd0.y + acc[2]*dd0.z + acc[3]*dd0.w
             + acc[4]*dd1.x + acc[5]*dd1.y + acc[6]*dd1.z + acc[7]*dd1.w;
    #pragma unroll
    for (int o = 16; o > 0; o >>= 1){
      ps += __shfl_xor(ps, o);
      pd += __shfl_xor(pd, o);
    }
    if (lane == 0){ s_next[node] = ps; d_next[node] = pd; }
  }
}

// ---- global add pool (batch sorted), f16 input: 1024 blocks ----
__device__ __forceinline__ int lbound(const int* a, int n, int v){
  int lo = 0, hi = n;
  while (lo < hi){ int mid = (lo + hi) >> 1; if (a[mid] < v) lo = mid + 1; else hi = mid; }
  return lo;
}

__global__ __launch_bounds__(256) void pool_kernel(const unsigned short* __restrict__ h16,
                                                   const int* __restrict__ batch,
                                                   float* __restrict__ pooled){
  int g = blockIdx.x, split = blockIdx.y, t = threadIdx.x;
  int lo = lbound(batch, NN, g);
  int hi = lbound(batch, NN, g + 1);
  int len = hi - lo;
  int chunk = (len + 15) >> 4;
  int b  = lo + split*chunk;
  int e2 = min(hi, b + chunk);
  float acc = 0.f;
  for (int i = b; i < e2; i++) acc += h2f(h16[(size_t)i*D_H + t]);
  atomicAdd(&pooled[g*D_H + t], acc);
}

// ---- final FC ----
__global__ __launch_bounds__(64) void fc_kernel(const float* __restrict__ pooled,
                                                const float* __restrict__ fcW,
                                                const float* __restrict__ fcb,
                                                float* __restrict__ out){
  int g = blockIdx.x, o = threadIdx.x;
  float acc = fcb[o];
  for (int k = 0; k < D_H; k++) acc += pooled[g*D_H + k] * fcW[k*D_OUT + o];
  out[g*D_OUT + o] = acc;
}

extern "C" void kernel_launch(void* const* d_in, const int* in_sizes, int n_in,
                              void* d_out, int out_size, void* d_ws, size_t ws_size,
                              hipStream_t stream){
  const float* x     = (const float*)d_in[0];
  const int*   ei    = (const int*)d_in[1];
  const int*   batch = (const int*)d_in[2];
  const float* W1  = (const float*)d_in[3];
  const float* as1 = (const float*)d_in[4];
  const float* ad1 = (const float*)d_in[5];
  const float* b1  = (const float*)d_in[6];
  const float* W2  = (const float*)d_in[7];
  const float* as2 = (const float*)d_in[8];
  const float* ad2 = (const float*)d_in[9];
  const float* b2  = (const float*)d_in[10];
  const float* W3  = (const float*)d_in[11];
  const float* as3 = (const float*)d_in[12];
  const float* ad3 = (const float*)d_in[13];
  const float* b3  = (const float*)d_in[14];
  const float* fcW = (const float*)d_in[15];
  const float* fcb = (const float*)d_in[16];

  const int* src = ei;
  const int* dst = ei + NE;

  char* p = (char*)d_ws;
  auto alloc = [&](size_t bytes) -> void* {
    void* r = (void*)p;
    p += (bytes + 255) & ~(size_t)255;
    return r;
  };
  unsigned short* h_a16 = (unsigned short*)alloc((size_t)NN*D_H*2);
  unsigned short* h_b16 = (unsigned short*)alloc((size_t)NN*D_H*2);
  unsigned short* xb    = (unsigned short*)alloc((size_t)NN*D_IN*2);
  unsigned short* Wt0   = (unsigned short*)alloc((size_t)256*D_IN*2);
  unsigned short* Wt1   = (unsigned short*)alloc((size_t)256*256*2);
  unsigned short* Wt2   = (unsigned short*)alloc((size_t)256*256*2);
  float* sA     = (float*)alloc((size_t)NN*4);
  float* dA     = (float*)alloc((size_t)NN*4);
  float* sB     = (float*)alloc((size_t)NN*4);
  float* dB     = (float*)alloc((size_t)NN*4);
  float* wv     = (float*)alloc((size_t)1280*4);
  int* deg      = (int*)alloc((size_t)NN*4);
  int* offs     = (int*)alloc((size_t)(NN+1)*4);
  int* cursor   = (int*)alloc((size_t)NN*4);
  int* bsum     = (int*)alloc((size_t)256*4);
  int* csr      = (int*)alloc((size_t)NE*4);
  float* pooled = (float*)alloc((size_t)NG*D_H*4);

  const int nblk = (NN + 255)/256;   // 196

  cast_wt_all<<<903, 256, 0, stream>>>(W1, W2, W3, as1, ad1, as2, ad2, as3, ad3,
                                       Wt0, Wt1, Wt2, wv, deg, pooled);
  prep_kernel<<<(NN*32 + 255)/256, 256, 0, stream>>>(x, xb, wv, sA, dA, dst, deg);
  scan_bsum<<<nblk, 256, 0, stream>>>(deg, bsum);
  scan_offs<<<nblk, 256, 0, stream>>>(deg, bsum, offs, cursor, nblk);
  scatter_csr<<<(NE + 255)/256, 256, 0, stream>>>(src, dst, cursor, csr);

  const int mgrid = (NN + 127)/128;
  const int agrid = (NN + 3)/4;

  gemm_f16<128><<<dim3(mgrid, 2), 256, 0, stream>>>(xb, Wt0, h_a16);
  agg_kernel<<<agrid, 256, 0, stream>>>(h_a16, offs, csr, sA, dA, b1, h_b16,
                                        wv + 256, wv + 512, sB, dB, 1);
  gemm_f16<256><<<dim3(mgrid, 2), 256, 0, stream>>>(h_b16, Wt1, h_a16);
  agg_kernel<<<agrid, 256, 0, stream>>>(h_a16, offs, csr, sB, dB, b2, h_b16,
                                        wv + 768, wv + 1024, sA, dA, 1);
  gemm_f16<256><<<dim3(mgrid, 2), 256, 0, stream>>>(h_b16, Wt2, h_a16);
  agg_kernel<<<agrid, 256, 0, stream>>>(h_a16, offs, csr, sA, dA, b3, h_b16,
                                        (const float*)nullptr, (const float*)nullptr,
                                        (float*)nullptr, (float*)nullptr, 0);

  pool_kernel<<<dim3(NG, 16), 256, 0, stream>>>(h_b16, batch, pooled);
  fc_kernel<<<NG, 64, 0, stream>>>(pooled, fcW, fcb, (float*)d_out);
}

// Round 12
// 441.783 us; speedup vs baseline: 1.1517x; 1.0780x over previous
//
#include <hip/hip_runtime.h>

#define NN 50000
#define NE 800000
#define D_IN 128
#define D_H 256
#define D_OUT 64
#define NG 64

typedef _Float16 f16;
typedef _Float16 f16x8 __attribute__((ext_vector_type(8)));
typedef _Float16 f16x2 __attribute__((ext_vector_type(2)));
typedef unsigned short u16x8 __attribute__((ext_vector_type(8)));
typedef float f32x4 __attribute__((ext_vector_type(4)));

__device__ __forceinline__ float lrelu(float x){ return x > 0.f ? x : 0.2f*x; }

__device__ __forceinline__ unsigned short f2h(float f){
  f16 h = (f16)f;
  return __builtin_bit_cast(unsigned short, h);
}
__device__ __forceinline__ float h2f(unsigned short b){
  return (float)__builtin_bit_cast(f16, b);
}

// async global->LDS, 16B per lane; lptr is wave-uniform base, lane i lands at base + i*16B
__device__ __forceinline__ void gll16(const unsigned short* g, unsigned short* l){
  __builtin_amdgcn_global_load_lds(
      (const __attribute__((address_space(1))) void*)g,
      (__attribute__((address_space(3))) void*)l,
      16, 0, 0);
}

// acc += h * w  (4x v_pk_fma_f16)
__device__ __forceinline__ void pkfma(f16x8& acc, u16x8 hraw, f16x2 w2){
  f16x8 hv = __builtin_bit_cast(f16x8, hraw);
  f16x2* a2 = (f16x2*)&acc;
  const f16x2* h2p = (const f16x2*)&hv;
  #pragma unroll
  for (int k = 0; k < 4; k++) a2[k] += h2p[k] * w2;
}

// ---- W [K][256] -> Wt packed in MFMA B-fragment order ----
__device__ __forceinline__ void cast_one_wt(const float* W, unsigned short* Wt, int K, int idx){
  int k = idx >> 8, n = idx & 255;
  int grp = (n >> 4)*(K >> 5) + (k >> 5);
  int within = ((((k >> 3) & 3) << 4) | (n & 15)) * 8 + (k & 7);
  Wt[grp*512 + within] = f2h(W[idx]);
}

// blocks 0..639: cast W1/W2/W3 | 640..642: wv vectors | 643..838: zero deg | 839..902: zero pooled
__global__ __launch_bounds__(256) void cast_wt_all(const float* __restrict__ W1,
                                                   const float* __restrict__ W2,
                                                   const float* __restrict__ W3,
                                                   const float* __restrict__ as1,
                                                   const float* __restrict__ ad1,
                                                   const float* __restrict__ as2,
                                                   const float* __restrict__ ad2,
                                                   const float* __restrict__ as3,
                                                   const float* __restrict__ ad3,
                                                   unsigned short* __restrict__ Wt0,
                                                   unsigned short* __restrict__ Wt1,
                                                   unsigned short* __restrict__ Wt2,
                                                   float* __restrict__ wv,
                                                   int* __restrict__ deg,
                                                   float* __restrict__ pooled){
  int b = blockIdx.x, t = threadIdx.x;
  if (b < 640){
    int e = b*256 + t;
    if (e < 32768)        cast_one_wt(W1, Wt0, 128, e);
    else if (e < 98304)   cast_one_wt(W2, Wt1, 256, e - 32768);
    else                  cast_one_wt(W3, Wt2, 256, e - 98304);
  } else if (b < 643){
    int L = b - 640;
    const float* W  = (L==0) ? W1 : ((L==1) ? W2 : W3);
    const float* av = (L==0) ? as1 : ((L==1) ? as2 : as3);
    const float* dv = (L==0) ? ad1 : ((L==1) ? ad2 : ad3);
    int K   = (L==0) ? 128 : 256;
    int off = (L==0) ? 0 : ((L==1) ? 256 : 768);
    int k = t;
    if (k < K){
      float ps = 0.f, pd = 0.f;
      for (int n = 0; n < 256; n += 4){
        float4 w  = *(const float4*)(W + k*256 + n);
        float4 a  = *(const float4*)(av + n);
        float4 d2 = *(const float4*)(dv + n);
        ps += w.x*a.x + w.y*a.y + w.z*a.z + w.w*a.w;
        pd += w.x*d2.x + w.y*d2.y + w.z*d2.z + w.w*d2.w;
      }
      wv[off + k]     = ps;
      wv[off + K + k] = pd;
    }
  } else if (b < 839){
    int i = (b - 643)*256 + t;
    if (i < NN) deg[i] = 0;
  } else {
    pooled[(b - 839)*256 + t] = 0.f;
  }
}

// ---- prep: cast x to f16 + s1/d1 + degree count (rank recorded -> atomic-free scatter) ----
__global__ __launch_bounds__(256) void prep_kernel(const float* __restrict__ x,
                                                   unsigned short* __restrict__ xb,
                                                   const float* __restrict__ wv,
                                                   float* __restrict__ s,
                                                   float* __restrict__ d,
                                                   const int* __restrict__ dst,
                                                   int* __restrict__ deg,
                                                   int* __restrict__ erank){
  int gid = blockIdx.x*256 + threadIdx.x;
  if (gid < NN*32){
    float4 v = ((const float4*)x)[gid];
    ushort4 o = { f2h(v.x), f2h(v.y), f2h(v.z), f2h(v.w) };
    ((ushort4*)xb)[gid] = o;
    int node = gid >> 5, sub = gid & 31;
    float4 ws = ((const float4*)wv)[sub];
    float4 wd = ((const float4*)(wv + 128))[sub];
    float ps = v.x*ws.x + v.y*ws.y + v.z*ws.z + v.w*ws.w;
    float pd = v.x*wd.x + v.y*wd.y + v.z*wd.z + v.w*wd.w;
    #pragma unroll
    for (int o2 = 16; o2 > 0; o2 >>= 1){
      ps += __shfl_down(ps, o2, 32);
      pd += __shfl_down(pd, o2, 32);
    }
    if (sub == 0){ s[node] = ps; d[node] = pd; }
  }
  if (gid < NE){
    int r = atomicAdd(&deg[dst[gid]], 1);
    erank[gid] = r;
  }
}

// ---- CSR build ----
__global__ __launch_bounds__(256) void scan_bsum(const int* __restrict__ deg,
                                                 int* __restrict__ bsum){
  __shared__ int sm[256];
  int b = blockIdx.x, t = threadIdx.x;
  int gid = b*256 + t;
  sm[t] = (gid < NN) ? deg[gid] : 0;
  __syncthreads();
  for (int off = 128; off > 0; off >>= 1){
    if (t < off) sm[t] += sm[t+off];
    __syncthreads();
  }
  if (t == 0) bsum[b] = sm[0];
}

__global__ __launch_bounds__(256) void scan_offs(const int* __restrict__ deg,
                                                 const int* __restrict__ bsum,
                                                 int* __restrict__ offs,
                                                 int nblk){
  __shared__ int sb[256];
  __shared__ int sm[256];
  int b = blockIdx.x, t = threadIdx.x;
  sb[t] = (t < nblk) ? bsum[t] : 0;
  __syncthreads();
  for (int off = 1; off < 256; off <<= 1){
    int v = (t >= off) ? sb[t-off] : 0;
    __syncthreads();
    sb[t] += v;
    __syncthreads();
  }
  int base = (b == 0) ? 0 : sb[b-1];
  int gid = b*256 + t;
  int v = (gid < NN) ? deg[gid] : 0;
  sm[t] = v;
  __syncthreads();
  for (int off = 1; off < 256; off <<= 1){
    int u = (t >= off) ? sm[t-off] : 0;
    __syncthreads();
    sm[t] += u;
    __syncthreads();
  }
  int incl = sm[t], excl = incl - v;
  if (gid < NN) offs[gid] = base + excl;
  if (gid == NN-1) offs[NN] = base + incl;
}

// atomic-free scatter: position = offs[dst] + rank (recorded in prep)
__global__ void scatter_csr(const int* __restrict__ src, const int* __restrict__ dst,
                            const int* __restrict__ offs, const int* __restrict__ erank,
                            int* __restrict__ csr_src){
  int e = blockIdx.x*256 + threadIdx.x;
  if (e < NE){
    int dd = dst[e];
    csr_src[offs[dd] + erank[e]] = src[e];
  }
}

// ---- f16 MFMA GEMM: global_load_lds staging (swizzle via permuted global chunk) ----
template<int K>
__global__ __launch_bounds__(256) void gemm_f16(const unsigned short* __restrict__ A,
                                                const unsigned short* __restrict__ Wt,
                                                unsigned short* __restrict__ C16){
  constexpr int KS   = 128;          // staged K per pass
  constexpr int NSTG = K / KS;       // 1 or 2
  __shared__ unsigned short As[128*132];   // stage: 128x128; epilogue: 128x132
  const int t = threadIdx.x;
  const int bm = blockIdx.x * 128;
  const int bn = blockIdx.y * 128;
  const int wave = t >> 6, lane = t & 63;
  const int wm = (wave >> 1) * 64, wn = (wave & 1) * 64;
  const int l15 = lane & 15, quad = lane >> 4;

  const int ls = lane & 15;          // staging slot within row
  const int lr = lane >> 4;          // staging row within 4-row group

  f32x4 acc[4][4];
  #pragma unroll
  for (int i = 0; i < 4; i++)
    #pragma unroll
    for (int j = 0; j < 4; j++){
      f32x4 z = {0.f, 0.f, 0.f, 0.f};
      acc[i][j] = z;
    }

  #pragma unroll
  for (int stg = 0; stg < NSTG; stg++){
    if (stg > 0) __syncthreads();    // previous MFMA reads must finish before overwrite
    // stage: each wave covers rows [wave*32, wave*32+32), 4 rows (1KB) per issue.
    // lane loads global chunk (ls ^ (row&7)) -> LDS lands at slot ls: swizzled layout,
    // identical to ds-written version; 16 lanes/row still cover one 256B segment.
    #pragma unroll
    for (int g = 0; g < 8; g++){
      int row = wave*32 + g*4 + lr;
      int gc  = ls ^ (row & 7);
      const unsigned short* gp = A + (size_t)(bm + row)*K + stg*KS + gc*8;
      gll16(gp, &As[(wave*32 + g*4)*128]);
    }
    __syncthreads();
    #pragma unroll
    for (int ksl = 0; ksl < KS/32; ksl++){
      const int ks = stg*(KS/32) + ksl;
      f16x8 af[4];
      const int pc = ((ksl*4 + quad) ^ (l15 & 7)) * 8;
      #pragma unroll
      for (int i = 0; i < 4; i++)
        af[i] = *(const f16x8*)(&As[(wm + i*16 + l15)*128 + pc]);
      #pragma unroll
      for (int j = 0; j < 4; j++){
        int nb = ((bn + wn) >> 4) + j;
        f16x8 bfr = *(const f16x8*)(Wt + ((size_t)(nb*(K>>5) + ks))*512 + lane*8);
        #pragma unroll
        for (int i = 0; i < 4; i++)
          acc[i][j] = __builtin_amdgcn_mfma_f32_16x16x32_f16(af[i], bfr, acc[i][j], 0, 0, 0);
      }
    }
  }

  // epilogue: pack f16 tile into LDS (stride 132), coalesced 16B stores
  __syncthreads();
  #pragma unroll
  for (int i = 0; i < 4; i++)
    #pragma unroll
    for (int j = 0; j < 4; j++)
      #pragma unroll
      for (int r = 0; r < 4; r++)
        As[(wm + i*16 + quad*4 + r)*132 + wn + j*16 + l15] = f2h(acc[i][j][r]);
  __syncthreads();
  {
    const int rl = t >> 1, hc = (t & 1)*64;
    const int grow = bm + rl;
    if (grow < NN){
      #pragma unroll
      for (int u = 0; u < 8; u++){
        u16x8 v = *(const u16x8*)(&As[rl*132 + hc + u*8]);
        *(u16x8*)(C16 + (size_t)grow*256 + bn + hc + u*8) = v;
      }
    }
  }
}

// ---- fused softmax + aggregation + next-layer s/d (round-8 structure) ----
__global__ __launch_bounds__(256) void agg_kernel(const unsigned short* __restrict__ h16,
                                                  const int* __restrict__ offs,
                                                  const int* __restrict__ csr_src,
                                                  const float* __restrict__ s,
                                                  const float* __restrict__ d,
                                                  const float* __restrict__ bias,
                                                  unsigned short* __restrict__ hout16,
                                                  const float* __restrict__ wv_s,
                                                  const float* __restrict__ wv_d,
                                                  float* __restrict__ s_next,
                                                  float* __restrict__ d_next,
                                                  int do_sd){
  __shared__ int2 meta[4][64];
  const int wvi = threadIdx.x >> 6;
  const int node = blockIdx.x*4 + wvi;
  const int lane = threadIdx.x & 63;
  if (node >= NN) return;
  const float d_i = d[node];
  const int beg = offs[node], end = offs[node+1];
  const int deg = end - beg;

  const int half = lane >> 5;
  const int c    = lane & 31;
  const u16x8* h8 = (const u16x8*)h16;

  f16x8 acc8 = {0,0,0,0,0,0,0,0};
  float inv_den;

  if (deg <= 63){
    int sj = 0;
    float e = -1e30f;
    if (lane < deg){
      sj = csr_src[beg + lane];
      e = lrelu(s[sj] + d_i);
    }
    float m = e;
    #pragma unroll
    for (int o = 32; o > 0; o >>= 1) m = fmaxf(m, __shfl_xor(m, o));
    const float e0 = lrelu(s[node] + d_i);
    m = fmaxf(m, e0);

    float w = 0.f;
    if (lane < deg) w = __expf(e - m);
    else if (lane == deg){ w = __expf(e0 - m); sj = node; }
    float den = w;
    #pragma unroll
    for (int o = 32; o > 0; o >>= 1) den += __shfl_xor(den, o);
    inv_den = 1.f / den;

    const int np = (deg + 8) & ~7;          // slots 0..deg (+self), padded; np <= 64
    f16 wh = (f16)w;
    f16x2 wp = {wh, wh};
    if (lane < np) meta[wvi][lane] = make_int2(sj, __builtin_bit_cast(int, wp));

    for (int eb = 0; eb < np; eb += 8){
      int2 m0 = meta[wvi][eb + half];
      int2 m1 = meta[wvi][eb + 2 + half];
      int2 m2 = meta[wvi][eb + 4 + half];
      int2 m3 = meta[wvi][eb + 6 + half];
      u16x8 h0 = h8[(size_t)m0.x*32 + c];
      u16x8 h1 = h8[(size_t)m1.x*32 + c];
      u16x8 h2 = h8[(size_t)m2.x*32 + c];
      u16x8 h3 = h8[(size_t)m3.x*32 + c];
      pkfma(acc8, h0, __builtin_bit_cast(f16x2, m0.y));
      pkfma(acc8, h1, __builtin_bit_cast(f16x2, m1.y));
      pkfma(acc8, h2, __builtin_bit_cast(f16x2, m2.y));
      pkfma(acc8, h3, __builtin_bit_cast(f16x2, m3.y));
    }
  } else {
    // correctness fallback (deg > 63)
    float m_l = -1e30f;
    for (int j = lane; j < deg; j += 64){
      int sj = csr_src[beg + j];
      m_l = fmaxf(m_l, lrelu(s[sj] + d_i));
    }
    #pragma unroll
    for (int o = 32; o > 0; o >>= 1) m_l = fmaxf(m_l, __shfl_xor(m_l, o));
    const float e0 = lrelu(s[node] + d_i);
    const float m = fmaxf(m_l, e0);
    float den_l = (lane == 0) ? __expf(e0 - m) : 0.f;
    for (int j = lane; j < deg; j += 64){
      int sj = csr_src[beg + j];
      den_l += __expf(lrelu(s[sj] + d_i) - m);
    }
    #pragma unroll
    for (int o = 32; o > 0; o >>= 1) den_l += __shfl_xor(den_l, o);
    inv_den = 1.f / den_l;

    if (half == 0){
      f16 w0h = (f16)__expf(e0 - m);
      f16x2 wp0 = {w0h, w0h};
      pkfma(acc8, h8[(size_t)node*32 + c], wp0);
    }
    for (int eb = beg; eb < end; eb += 4){
      int e1 = eb + half;
      int e2 = e1 + 2;
      int sa = csr_src[min(e1, end-1)];
      int sb = csr_src[min(e2, end-1)];
      float wa = (e1 < end) ? __expf(lrelu(s[sa] + d_i) - m) : 0.f;
      float wb = (e2 < end) ? __expf(lrelu(s[sb] + d_i) - m) : 0.f;
      f16 wah = (f16)wa, wbh = (f16)wb;
      f16x2 wap = {wah, wah}, wbp = {wbh, wbh};
      pkfma(acc8, h8[(size_t)sa*32 + c], wap);
      pkfma(acc8, h8[(size_t)sb*32 + c], wbp);
    }
  }

  // f32 + normalize, merge halves
  float acc[8];
  #pragma unroll
  for (int i = 0; i < 8; i++) acc[i] = (float)acc8[i] * inv_den;
  #pragma unroll
  for (int i = 0; i < 8; i++) acc[i] += __shfl_xor(acc[i], 32);

  const float4* bb = (const float4*)(bias + c*8);
  float4 b0 = bb[0], b1 = bb[1];
  acc[0] = fmaxf(acc[0] + b0.x, 0.f); acc[1] = fmaxf(acc[1] + b0.y, 0.f);
  acc[2] = fmaxf(acc[2] + b0.z, 0.f); acc[3] = fmaxf(acc[3] + b0.w, 0.f);
  acc[4] = fmaxf(acc[4] + b1.x, 0.f); acc[5] = fmaxf(acc[5] + b1.y, 0.f);
  acc[6] = fmaxf(acc[6] + b1.z, 0.f); acc[7] = fmaxf(acc[7] + b1.w, 0.f);

  if (half == 0){
    u16x8 o;
    #pragma unroll
    for (int i = 0; i < 8; i++) o[i] = f2h(acc[i]);
    ((u16x8*)hout16)[(size_t)node*32 + c] = o;
  }

  if (do_sd){
    const float4* ws4 = (const float4*)(wv_s + c*8);
    const float4* wd4 = (const float4*)(wv_d + c*8);
    float4 s0 = ws4[0], s1 = ws4[1], dd0 = wd4[0], dd1 = wd4[1];
    float ps = acc[0]*s0.x + acc[1]*s0.y + acc[2]*s0.z + acc[3]*s0.w
             + acc[4]*s1.x + acc[5]*s1.y + acc[6]*s1.z + acc[7]*s1.w;
    float pd = acc[0]*dd0.x + acc[1]*dd0.y + acc[2]*dd0.z + acc[3]*dd0.w
             + acc[4]*dd1.x + acc[5]*dd1.y + acc[6]*dd1.z + acc[7]*dd1.w;
    #pragma unroll
    for (int o = 16; o > 0; o >>= 1){
      ps += __shfl_xor(ps, o);
      pd += __shfl_xor(pd, o);
    }
    if (lane == 0){ s_next[node] = ps; d_next[node] = pd; }
  }
}

// ---- global add pool (batch sorted), f16 input: 1024 blocks ----
__device__ __forceinline__ int lbound(const int* a, int n, int v){
  int lo = 0, hi = n;
  while (lo < hi){ int mid = (lo + hi) >> 1; if (a[mid] < v) lo = mid + 1; else hi = mid; }
  return lo;
}

__global__ __launch_bounds__(256) void pool_kernel(const unsigned short* __restrict__ h16,
                                                   const int* __restrict__ batch,
                                                   float* __restrict__ pooled){
  int g = blockIdx.x, split = blockIdx.y, t = threadIdx.x;
  int lo = lbound(batch, NN, g);
  int hi = lbound(batch, NN, g + 1);
  int len = hi - lo;
  int chunk = (len + 15) >> 4;
  int b  = lo + split*chunk;
  int e2 = min(hi, b + chunk);
  float acc = 0.f;
  for (int i = b; i < e2; i++) acc += h2f(h16[(size_t)i*D_H + t]);
  atomicAdd(&pooled[g*D_H + t], acc);
}

// ---- final FC ----
__global__ __launch_bounds__(64) void fc_kernel(const float* __restrict__ pooled,
                                                const float* __restrict__ fcW,
                                                const float* __restrict__ fcb,
                                                float* __restrict__ out){
  int g = blockIdx.x, o = threadIdx.x;
  float acc = fcb[o];
  for (int k = 0; k < D_H; k++) acc += pooled[g*D_H + k] * fcW[k*D_OUT + o];
  out[g*D_OUT + o] = acc;
}

extern "C" void kernel_launch(void* const* d_in, const int* in_sizes, int n_in,
                              void* d_out, int out_size, void* d_ws, size_t ws_size,
                              hipStream_t stream){
  const float* x     = (const float*)d_in[0];
  const int*   ei    = (const int*)d_in[1];
  const int*   batch = (const int*)d_in[2];
  const float* W1  = (const float*)d_in[3];
  const float* as1 = (const float*)d_in[4];
  const float* ad1 = (const float*)d_in[5];
  const float* b1  = (const float*)d_in[6];
  const float* W2  = (const float*)d_in[7];
  const float* as2 = (const float*)d_in[8];
  const float* ad2 = (const float*)d_in[9];
  const float* b2  = (const float*)d_in[10];
  const float* W3  = (const float*)d_in[11];
  const float* as3 = (const float*)d_in[12];
  const float* ad3 = (const float*)d_in[13];
  const float* b3  = (const float*)d_in[14];
  const float* fcW = (const float*)d_in[15];
  const float* fcb = (const float*)d_in[16];

  const int* src = ei;
  const int* dst = ei + NE;

  char* p = (char*)d_ws;
  auto alloc = [&](size_t bytes) -> void* {
    void* r = (void*)p;
    p += (bytes + 255) & ~(size_t)255;
    return r;
  };
  unsigned short* h_a16 = (unsigned short*)alloc((size_t)NN*D_H*2);
  unsigned short* h_b16 = (unsigned short*)alloc((size_t)NN*D_H*2);
  unsigned short* xb    = (unsigned short*)alloc((size_t)NN*D_IN*2);
  unsigned short* Wt0   = (unsigned short*)alloc((size_t)256*D_IN*2);
  unsigned short* Wt1   = (unsigned short*)alloc((size_t)256*256*2);
  unsigned short* Wt2   = (unsigned short*)alloc((size_t)256*256*2);
  float* sA     = (float*)alloc((size_t)NN*4);
  float* dA     = (float*)alloc((size_t)NN*4);
  float* sB     = (float*)alloc((size_t)NN*4);
  float* dB     = (float*)alloc((size_t)NN*4);
  float* wv     = (float*)alloc((size_t)1280*4);
  int* deg      = (int*)alloc((size_t)NN*4);
  int* offs     = (int*)alloc((size_t)(NN+1)*4);
  int* erank    = (int*)alloc((size_t)NE*4);
  int* bsum     = (int*)alloc((size_t)256*4);
  int* csr      = (int*)alloc((size_t)NE*4);
  float* pooled = (float*)alloc((size_t)NG*D_H*4);

  const int nblk = (NN + 255)/256;   // 196

  cast_wt_all<<<903, 256, 0, stream>>>(W1, W2, W3, as1, ad1, as2, ad2, as3, ad3,
                                       Wt0, Wt1, Wt2, wv, deg, pooled);
  prep_kernel<<<(NN*32 + 255)/256, 256, 0, stream>>>(x, xb, wv, sA, dA, dst, deg, erank);
  scan_bsum<<<nblk, 256, 0, stream>>>(deg, bsum);
  scan_offs<<<nblk, 256, 0, stream>>>(deg, bsum, offs, nblk);
  scatter_csr<<<(NE + 255)/256, 256, 0, stream>>>(src, dst, offs, erank, csr);

  const int mgrid = (NN + 127)/128;
  const int agrid = (NN + 3)/4;

  gemm_f16<128><<<dim3(mgrid, 2), 256, 0, stream>>>(xb, Wt0, h_a16);
  agg_kernel<<<agrid, 256, 0, stream>>>(h_a16, offs, csr, sA, dA, b1, h_b16,
                                        wv + 256, wv + 512, sB, dB, 1);
  gemm_f16<256><<<dim3(mgrid, 2), 256, 0, stream>>>(h_b16, Wt1, h_a16);
  agg_kernel<<<agrid, 256, 0, stream>>>(h_a16, offs, csr, sB, dB, b2, h_b16,
                                        wv + 768, wv + 1024, sA, dA, 1);
  gemm_f16<256><<<dim3(mgrid, 2), 256, 0, stream>>>(h_b16, Wt2, h_a16);
  agg_kernel<<<agrid, 256, 0, stream>>>(h_a16, offs, csr, sA, dA, b3, h_b16,
                                        (const float*)nullptr, (const float*)nullptr,
                                        (float*)nullptr, (float*)nullptr, 0);

  pool_kernel<<<dim3(NG, 16), 256, 0, stream>>>(h_b16, batch, pooled);
  fc_kernel<<<NG, 64, 0, stream>>>(pooled, fcW, fcb, (float*)d_out);
}

// Round 13
// 434.575 us; speedup vs baseline: 1.1708x; 1.0166x over previous
//
#include <hip/hip_runtime.h>

#define NN 50000
#define NE 800000
#define D_IN 128
#define D_H 256
#define D_OUT 64
#define NG 64

typedef _Float16 f16;
typedef _Float16 f16x8 __attribute__((ext_vector_type(8)));
typedef _Float16 f16x2 __attribute__((ext_vector_type(2)));
typedef unsigned short u16x8 __attribute__((ext_vector_type(8)));
typedef float f32x4 __attribute__((ext_vector_type(4)));

__device__ __forceinline__ float lrelu(float x){ return x > 0.f ? x : 0.2f*x; }

__device__ __forceinline__ unsigned short f2h(float f){
  f16 h = (f16)f;
  return __builtin_bit_cast(unsigned short, h);
}
__device__ __forceinline__ float h2f(unsigned short b){
  return (float)__builtin_bit_cast(f16, b);
}

// async global->LDS, 16B per lane; lptr is wave-uniform base, lane i lands at base + i*16B
__device__ __forceinline__ void gll16(const unsigned short* g, unsigned short* l){
  __builtin_amdgcn_global_load_lds(
      (const __attribute__((address_space(1))) void*)g,
      (__attribute__((address_space(3))) void*)l,
      16, 0, 0);
}

// acc += h * w  (4x v_pk_fma_f16)
__device__ __forceinline__ void pkfma(f16x8& acc, u16x8 hraw, f16x2 w2){
  f16x8 hv = __builtin_bit_cast(f16x8, hraw);
  f16x2* a2 = (f16x2*)&acc;
  const f16x2* h2p = (const f16x2*)&hv;
  #pragma unroll
  for (int k = 0; k < 4; k++) a2[k] += h2p[k] * w2;
}

// ---- W [K][256] -> Wt packed in MFMA B-fragment order ----
__device__ __forceinline__ void cast_one_wt(const float* W, unsigned short* Wt, int K, int idx){
  int k = idx >> 8, n = idx & 255;
  int grp = (n >> 4)*(K >> 5) + (k >> 5);
  int within = ((((k >> 3) & 3) << 4) | (n & 15)) * 8 + (k & 7);
  Wt[grp*512 + within] = f2h(W[idx]);
}

// blocks 0..639: cast W1/W2/W3 | 640..642: wv vectors | 643..838: zero deg | 839..902: zero pooled
__global__ __launch_bounds__(256) void cast_wt_all(const float* __restrict__ W1,
                                                   const float* __restrict__ W2,
                                                   const float* __restrict__ W3,
                                                   const float* __restrict__ as1,
                                                   const float* __restrict__ ad1,
                                                   const float* __restrict__ as2,
                                                   const float* __restrict__ ad2,
                                                   const float* __restrict__ as3,
                                                   const float* __restrict__ ad3,
                                                   unsigned short* __restrict__ Wt0,
                                                   unsigned short* __restrict__ Wt1,
                                                   unsigned short* __restrict__ Wt2,
                                                   float* __restrict__ wv,
                                                   int* __restrict__ deg,
                                                   float* __restrict__ pooled){
  int b = blockIdx.x, t = threadIdx.x;
  if (b < 640){
    int e = b*256 + t;
    if (e < 32768)        cast_one_wt(W1, Wt0, 128, e);
    else if (e < 98304)   cast_one_wt(W2, Wt1, 256, e - 32768);
    else                  cast_one_wt(W3, Wt2, 256, e - 98304);
  } else if (b < 643){
    int L = b - 640;
    const float* W  = (L==0) ? W1 : ((L==1) ? W2 : W3);
    const float* av = (L==0) ? as1 : ((L==1) ? as2 : as3);
    const float* dv = (L==0) ? ad1 : ((L==1) ? ad2 : ad3);
    int K   = (L==0) ? 128 : 256;
    int off = (L==0) ? 0 : ((L==1) ? 256 : 768);
    int k = t;
    if (k < K){
      float ps = 0.f, pd = 0.f;
      for (int n = 0; n < 256; n += 4){
        float4 w  = *(const float4*)(W + k*256 + n);
        float4 a  = *(const float4*)(av + n);
        float4 d2 = *(const float4*)(dv + n);
        ps += w.x*a.x + w.y*a.y + w.z*a.z + w.w*a.w;
        pd += w.x*d2.x + w.y*d2.y + w.z*d2.z + w.w*d2.w;
      }
      wv[off + k]     = ps;
      wv[off + K + k] = pd;
    }
  } else if (b < 839){
    int i = (b - 643)*256 + t;
    if (i < NN) deg[i] = 0;
  } else {
    pooled[(b - 839)*256 + t] = 0.f;
  }
}

// ---- prep: cast x to f16 + s1/d1 + degree count (rank recorded -> atomic-free scatter) ----
__global__ __launch_bounds__(256) void prep_kernel(const float* __restrict__ x,
                                                   unsigned short* __restrict__ xb,
                                                   const float* __restrict__ wv,
                                                   float* __restrict__ s,
                                                   float* __restrict__ d,
                                                   const int* __restrict__ dst,
                                                   int* __restrict__ deg,
                                                   int* __restrict__ erank){
  int gid = blockIdx.x*256 + threadIdx.x;
  if (gid < NN*32){
    float4 v = ((const float4*)x)[gid];
    ushort4 o = { f2h(v.x), f2h(v.y), f2h(v.z), f2h(v.w) };
    ((ushort4*)xb)[gid] = o;
    int node = gid >> 5, sub = gid & 31;
    float4 ws = ((const float4*)wv)[sub];
    float4 wd = ((const float4*)(wv + 128))[sub];
    float ps = v.x*ws.x + v.y*ws.y + v.z*ws.z + v.w*ws.w;
    float pd = v.x*wd.x + v.y*wd.y + v.z*wd.z + v.w*wd.w;
    #pragma unroll
    for (int o2 = 16; o2 > 0; o2 >>= 1){
      ps += __shfl_down(ps, o2, 32);
      pd += __shfl_down(pd, o2, 32);
    }
    if (sub == 0){ s[node] = ps; d[node] = pd; }
  }
  if (gid < NE){
    int r = atomicAdd(&deg[dst[gid]], 1);
    erank[gid] = r;
  }
}

// ---- CSR build ----
__global__ __launch_bounds__(256) void scan_bsum(const int* __restrict__ deg,
                                                 int* __restrict__ bsum){
  __shared__ int sm[256];
  int b = blockIdx.x, t = threadIdx.x;
  int gid = b*256 + t;
  sm[t] = (gid < NN) ? deg[gid] : 0;
  __syncthreads();
  for (int off = 128; off > 0; off >>= 1){
    if (t < off) sm[t] += sm[t+off];
    __syncthreads();
  }
  if (t == 0) bsum[b] = sm[0];
}

__global__ __launch_bounds__(256) void scan_offs(const int* __restrict__ deg,
                                                 const int* __restrict__ bsum,
                                                 int* __restrict__ offs,
                                                 int nblk){
  __shared__ int sb[256];
  __shared__ int sm[256];
  int b = blockIdx.x, t = threadIdx.x;
  sb[t] = (t < nblk) ? bsum[t] : 0;
  __syncthreads();
  for (int off = 1; off < 256; off <<= 1){
    int v = (t >= off) ? sb[t-off] : 0;
    __syncthreads();
    sb[t] += v;
    __syncthreads();
  }
  int base = (b == 0) ? 0 : sb[b-1];
  int gid = b*256 + t;
  int v = (gid < NN) ? deg[gid] : 0;
  sm[t] = v;
  __syncthreads();
  for (int off = 1; off < 256; off <<= 1){
    int u = (t >= off) ? sm[t-off] : 0;
    __syncthreads();
    sm[t] += u;
    __syncthreads();
  }
  int incl = sm[t], excl = incl - v;
  if (gid < NN) offs[gid] = base + excl;
  if (gid == NN-1) offs[NN] = base + incl;
}

// atomic-free scatter: position = offs[dst] + rank (recorded in prep)
__global__ void scatter_csr(const int* __restrict__ src, const int* __restrict__ dst,
                            const int* __restrict__ offs, const int* __restrict__ erank,
                            int* __restrict__ csr_src){
  int e = blockIdx.x*256 + threadIdx.x;
  if (e < NE){
    int dd = dst[e];
    csr_src[offs[dd] + erank[e]] = src[e];
  }
}

// ---- f16 MFMA GEMM: global_load_lds staging + B-fragment software pipeline ----
template<int K>
__global__ __launch_bounds__(256) void gemm_f16(const unsigned short* __restrict__ A,
                                                const unsigned short* __restrict__ Wt,
                                                unsigned short* __restrict__ C16){
  constexpr int KS   = 128;          // staged K per pass
  constexpr int NSTG = K / KS;       // 1 or 2
  constexpr int NKS  = K / 32;       // total ksteps
  __shared__ unsigned short As[128*132];   // stage: 128x128; epilogue: 128x132
  const int t = threadIdx.x;
  const int bm = blockIdx.x * 128;
  const int bn = blockIdx.y * 128;
  const int wave = t >> 6, lane = t & 63;
  const int wm = (wave >> 1) * 64, wn = (wave & 1) * 64;
  const int l15 = lane & 15, quad = lane >> 4;

  const int ls = lane & 15;          // staging slot within row
  const int lr = lane >> 4;          // staging row within 4-row group

  // B-fragment pointer for (kstep, j)
  const int nb0 = (bn + wn) >> 4;
  #define BPTR(KSI, J) ((const f16x8*)(Wt + ((size_t)((nb0 + (J))*(K>>5) + (KSI)))*512 + lane*8))

  f32x4 acc[4][4];
  #pragma unroll
  for (int i = 0; i < 4; i++)
    #pragma unroll
    for (int j = 0; j < 4; j++){
      f32x4 z = {0.f, 0.f, 0.f, 0.f};
      acc[i][j] = z;
    }

  // prime B pipeline (kstep 0) — issued before the barrier so it overlaps A staging
  f16x8 bcur[4];

  #pragma unroll
  for (int stg = 0; stg < NSTG; stg++){
    if (stg > 0) __syncthreads();    // previous MFMA reads must finish before overwrite
    // stage A panel: each wave covers rows [wave*32, wave*32+32), 4 rows (1KB) per issue;
    // lane fetches permuted global chunk so LDS lands pre-swizzled.
    #pragma unroll
    for (int g = 0; g < 8; g++){
      int row = wave*32 + g*4 + lr;
      int gc  = ls ^ (row & 7);
      const unsigned short* gp = A + (size_t)(bm + row)*K + stg*KS + gc*8;
      gll16(gp, &As[(wave*32 + g*4)*128]);
    }
    if (stg == 0){
      #pragma unroll
      for (int j = 0; j < 4; j++) bcur[j] = *BPTR(0, j);
    }
    __syncthreads();
    #pragma unroll
    for (int ksl = 0; ksl < KS/32; ksl++){
      const int ks = stg*(KS/32) + ksl;
      // prefetch next kstep's B fragments (crosses stage boundary harmlessly)
      f16x8 bnxt[4];
      if (ks + 1 < NKS){
        #pragma unroll
        for (int j = 0; j < 4; j++) bnxt[j] = *BPTR(ks + 1, j);
      }
      f16x8 af[4];
      const int pc = ((ksl*4 + quad) ^ (l15 & 7)) * 8;
      #pragma unroll
      for (int i = 0; i < 4; i++)
        af[i] = *(const f16x8*)(&As[(wm + i*16 + l15)*128 + pc]);
      #pragma unroll
      for (int j = 0; j < 4; j++)
        #pragma unroll
        for (int i = 0; i < 4; i++)
          acc[i][j] = __builtin_amdgcn_mfma_f32_16x16x32_f16(af[i], bcur[j], acc[i][j], 0, 0, 0);
      if (ks + 1 < NKS){
        #pragma unroll
        for (int j = 0; j < 4; j++) bcur[j] = bnxt[j];
      }
    }
  }
  #undef BPTR

  // epilogue: pack f16 tile into LDS (stride 132), coalesced 16B stores
  __syncthreads();
  #pragma unroll
  for (int i = 0; i < 4; i++)
    #pragma unroll
    for (int j = 0; j < 4; j++)
      #pragma unroll
      for (int r = 0; r < 4; r++)
        As[(wm + i*16 + quad*4 + r)*132 + wn + j*16 + l15] = f2h(acc[i][j][r]);
  __syncthreads();
  {
    const int rl = t >> 1, hc = (t & 1)*64;
    const int grow = bm + rl;
    if (grow < NN){
      #pragma unroll
      for (int u = 0; u < 8; u++){
        u16x8 v = *(const u16x8*)(&As[rl*132 + hc + u*8]);
        *(u16x8*)(C16 + (size_t)grow*256 + bn + hc + u*8) = v;
      }
    }
  }
}

// ---- fused softmax + aggregation + next-layer s/d (round-8 structure) ----
__global__ __launch_bounds__(256) void agg_kernel(const unsigned short* __restrict__ h16,
                                                  const int* __restrict__ offs,
                                                  const int* __restrict__ csr_src,
                                                  const float* __restrict__ s,
                                                  const float* __restrict__ d,
                                                  const float* __restrict__ bias,
                                                  unsigned short* __restrict__ hout16,
                                                  const float* __restrict__ wv_s,
                                                  const float* __restrict__ wv_d,
                                                  float* __restrict__ s_next,
                                                  float* __restrict__ d_next,
                                                  int do_sd){
  __shared__ int2 meta[4][64];
  const int wvi = threadIdx.x >> 6;
  const int node = blockIdx.x*4 + wvi;
  const int lane = threadIdx.x & 63;
  if (node >= NN) return;
  const float d_i = d[node];
  const int beg = offs[node], end = offs[node+1];
  const int deg = end - beg;

  const int half = lane >> 5;
  const int c    = lane & 31;
  const u16x8* h8 = (const u16x8*)h16;

  f16x8 acc8 = {0,0,0,0,0,0,0,0};
  float inv_den;

  if (deg <= 63){
    int sj = 0;
    float e = -1e30f;
    if (lane < deg){
      sj = csr_src[beg + lane];
      e = lrelu(s[sj] + d_i);
    }
    float m = e;
    #pragma unroll
    for (int o = 32; o > 0; o >>= 1) m = fmaxf(m, __shfl_xor(m, o));
    const float e0 = lrelu(s[node] + d_i);
    m = fmaxf(m, e0);

    float w = 0.f;
    if (lane < deg) w = __expf(e - m);
    else if (lane == deg){ w = __expf(e0 - m); sj = node; }
    float den = w;
    #pragma unroll
    for (int o = 32; o > 0; o >>= 1) den += __shfl_xor(den, o);
    inv_den = 1.f / den;

    const int np = (deg + 8) & ~7;          // slots 0..deg (+self), padded; np <= 64
    f16 wh = (f16)w;
    f16x2 wp = {wh, wh};
    if (lane < np) meta[wvi][lane] = make_int2(sj, __builtin_bit_cast(int, wp));

    for (int eb = 0; eb < np; eb += 8){
      int2 m0 = meta[wvi][eb + half];
      int2 m1 = meta[wvi][eb + 2 + half];
      int2 m2 = meta[wvi][eb + 4 + half];
      int2 m3 = meta[wvi][eb + 6 + half];
      u16x8 h0 = h8[(size_t)m0.x*32 + c];
      u16x8 h1 = h8[(size_t)m1.x*32 + c];
      u16x8 h2 = h8[(size_t)m2.x*32 + c];
      u16x8 h3 = h8[(size_t)m3.x*32 + c];
      pkfma(acc8, h0, __builtin_bit_cast(f16x2, m0.y));
      pkfma(acc8, h1, __builtin_bit_cast(f16x2, m1.y));
      pkfma(acc8, h2, __builtin_bit_cast(f16x2, m2.y));
      pkfma(acc8, h3, __builtin_bit_cast(f16x2, m3.y));
    }
  } else {
    // correctness fallback (deg > 63)
    float m_l = -1e30f;
    for (int j = lane; j < deg; j += 64){
      int sj = csr_src[beg + j];
      m_l = fmaxf(m_l, lrelu(s[sj] + d_i));
    }
    #pragma unroll
    for (int o = 32; o > 0; o >>= 1) m_l = fmaxf(m_l, __shfl_xor(m_l, o));
    const float e0 = lrelu(s[node] + d_i);
    const float m = fmaxf(m_l, e0);
    float den_l = (lane == 0) ? __expf(e0 - m) : 0.f;
    for (int j = lane; j < deg; j += 64){
      int sj = csr_src[beg + j];
      den_l += __expf(lrelu(s[sj] + d_i) - m);
    }
    #pragma unroll
    for (int o = 32; o > 0; o >>= 1) den_l += __shfl_xor(den_l, o);
    inv_den = 1.f / den_l;

    if (half == 0){
      f16 w0h = (f16)__expf(e0 - m);
      f16x2 wp0 = {w0h, w0h};
      pkfma(acc8, h8[(size_t)node*32 + c], wp0);
    }
    for (int eb = beg; eb < end; eb += 4){
      int e1 = eb + half;
      int e2 = e1 + 2;
      int sa = csr_src[min(e1, end-1)];
      int sb = csr_src[min(e2, end-1)];
      float wa = (e1 < end) ? __expf(lrelu(s[sa] + d_i) - m) : 0.f;
      float wb = (e2 < end) ? __expf(lrelu(s[sb] + d_i) - m) : 0.f;
      f16 wah = (f16)wa, wbh = (f16)wb;
      f16x2 wap = {wah, wah}, wbp = {wbh, wbh};
      pkfma(acc8, h8[(size_t)sa*32 + c], wap);
      pkfma(acc8, h8[(size_t)sb*32 + c], wbp);
    }
  }

  // f32 + normalize, merge halves
  float acc[8];
  #pragma unroll
  for (int i = 0; i < 8; i++) acc[i] = (float)acc8[i] * inv_den;
  #pragma unroll
  for (int i = 0; i < 8; i++) acc[i] += __shfl_xor(acc[i], 32);

  const float4* bb = (const float4*)(bias + c*8);
  float4 b0 = bb[0], b1 = bb[1];
  acc[0] = fmaxf(acc[0] + b0.x, 0.f); acc[1] = fmaxf(acc[1] + b0.y, 0.f);
  acc[2] = fmaxf(acc[2] + b0.z, 0.f); acc[3] = fmaxf(acc[3] + b0.w, 0.f);
  acc[4] = fmaxf(acc[4] + b1.x, 0.f); acc[5] = fmaxf(acc[5] + b1.y, 0.f);
  acc[6] = fmaxf(acc[6] + b1.z, 0.f); acc[7] = fmaxf(acc[7] + b1.w, 0.f);

  if (half == 0){
    u16x8 o;
    #pragma unroll
    for (int i = 0; i < 8; i++) o[i] = f2h(acc[i]);
    ((u16x8*)hout16)[(size_t)node*32 + c] = o;
  }

  if (do_sd){
    const float4* ws4 = (const float4*)(wv_s + c*8);
    const float4* wd4 = (const float4*)(wv_d + c*8);
    float4 s0 = ws4[0], s1 = ws4[1], dd0 = wd4[0], dd1 = wd4[1];
    float ps = acc[0]*s0.x + acc[1]*s0.y + acc[2]*s0.z + acc[3]*s0.w
             + acc[4]*s1.x + acc[5]*s1.y + acc[6]*s1.z + acc[7]*s1.w;
    float pd = acc[0]*dd0.x + acc[1]*dd0.y + acc[2]*dd0.z + acc[3]*dd0.w
             + acc[4]*dd1.x + acc[5]*dd1.y + acc[6]*dd1.z + acc[7]*dd1.w;
    #pragma unroll
    for (int o = 16; o > 0; o >>= 1){
      ps += __shfl_xor(ps, o);
      pd += __shfl_xor(pd, o);
    }
    if (lane == 0){ s_next[node] = ps; d_next[node] = pd; }
  }
}

// ---- global add pool (batch sorted), f16 input: 1024 blocks ----
__device__ __forceinline__ int lbound(const int* a, int n, int v){
  int lo = 0, hi = n;
  while (lo < hi){ int mid = (lo + hi) >> 1; if (a[mid] < v) lo = mid + 1; else hi = mid; }
  return lo;
}

__global__ __launch_bounds__(256) void pool_kernel(const unsigned short* __restrict__ h16,
                                                   const int* __restrict__ batch,
                                                   float* __restrict__ pooled){
  int g = blockIdx.x, split = blockIdx.y, t = threadIdx.x;
  int lo = lbound(batch, NN, g);
  int hi = lbound(batch, NN, g + 1);
  int len = hi - lo;
  int chunk = (len + 15) >> 4;
  int b  = lo + split*chunk;
  int e2 = min(hi, b + chunk);
  float acc = 0.f;
  for (int i = b; i < e2; i++) acc += h2f(h16[(size_t)i*D_H + t]);
  atomicAdd(&pooled[g*D_H + t], acc);
}

// ---- final FC ----
__global__ __launch_bounds__(64) void fc_kernel(const float* __restrict__ pooled,
                                                const float* __restrict__ fcW,
                                                const float* __restrict__ fcb,
                                                float* __restrict__ out){
  int g = blockIdx.x, o = threadIdx.x;
  float acc = fcb[o];
  for (int k = 0; k < D_H; k++) acc += pooled[g*D_H + k] * fcW[k*D_OUT + o];
  out[g*D_OUT + o] = acc;
}

extern "C" void kernel_launch(void* const* d_in, const int* in_sizes, int n_in,
                              void* d_out, int out_size, void* d_ws, size_t ws_size,
                              hipStream_t stream){
  const float* x     = (const float*)d_in[0];
  const int*   ei    = (const int*)d_in[1];
  const int*   batch = (const int*)d_in[2];
  const float* W1  = (const float*)d_in[3];
  const float* as1 = (const float*)d_in[4];
  const float* ad1 = (const float*)d_in[5];
  const float* b1  = (const float*)d_in[6];
  const float* W2  = (const float*)d_in[7];
  const float* as2 = (const float*)d_in[8];
  const float* ad2 = (const float*)d_in[9];
  const float* b2  = (const float*)d_in[10];
  const float* W3  = (const float*)d_in[11];
  const float* as3 = (const float*)d_in[12];
  const float* ad3 = (const float*)d_in[13];
  const float* b3  = (const float*)d_in[14];
  const float* fcW = (const float*)d_in[15];
  const float* fcb = (const float*)d_in[16];

  const int* src = ei;
  const int* dst = ei + NE;

  char* p = (char*)d_ws;
  auto alloc = [&](size_t bytes) -> void* {
    void* r = (void*)p;
    p += (bytes + 255) & ~(size_t)255;
    return r;
  };
  unsigned short* h_a16 = (unsigned short*)alloc((size_t)NN*D_H*2);
  unsigned short* h_b16 = (unsigned short*)alloc((size_t)NN*D_H*2);
  unsigned short* xb    = (unsigned short*)alloc((size_t)NN*D_IN*2);
  unsigned short* Wt0   = (unsigned short*)alloc((size_t)256*D_IN*2);
  unsigned short* Wt1   = (unsigned short*)alloc((size_t)256*256*2);
  unsigned short* Wt2   = (unsigned short*)alloc((size_t)256*256*2);
  float* sA     = (float*)alloc((size_t)NN*4);
  float* dA     = (float*)alloc((size_t)NN*4);
  float* sB     = (float*)alloc((size_t)NN*4);
  float* dB     = (float*)alloc((size_t)NN*4);
  float* wv     = (float*)alloc((size_t)1280*4);
  int* deg      = (int*)alloc((size_t)NN*4);
  int* offs     = (int*)alloc((size_t)(NN+1)*4);
  int* erank    = (int*)alloc((size_t)NE*4);
  int* bsum     = (int*)alloc((size_t)256*4);
  int* csr      = (int*)alloc((size_t)NE*4);
  float* pooled = (float*)alloc((size_t)NG*D_H*4);

  const int nblk = (NN + 255)/256;   // 196

  cast_wt_all<<<903, 256, 0, stream>>>(W1, W2, W3, as1, ad1, as2, ad2, as3, ad3,
                                       Wt0, Wt1, Wt2, wv, deg, pooled);
  prep_kernel<<<(NN*32 + 255)/256, 256, 0, stream>>>(x, xb, wv, sA, dA, dst, deg, erank);
  scan_bsum<<<nblk, 256, 0, stream>>>(deg, bsum);
  scan_offs<<<nblk, 256, 0, stream>>>(deg, bsum, offs, nblk);
  scatter_csr<<<(NE + 255)/256, 256, 0, stream>>>(src, dst, offs, erank, csr);

  const int mgrid = (NN + 127)/128;
  const int agrid = (NN + 3)/4;

  gemm_f16<128><<<dim3(mgrid, 2), 256, 0, stream>>>(xb, Wt0, h_a16);
  agg_kernel<<<agrid, 256, 0, stream>>>(h_a16, offs, csr, sA, dA, b1, h_b16,
                                        wv + 256, wv + 512, sB, dB, 1);
  gemm_f16<256><<<dim3(mgrid, 2), 256, 0, stream>>>(h_b16, Wt1, h_a16);
  agg_kernel<<<agrid, 256, 0, stream>>>(h_a16, offs, csr, sB, dB, b2, h_b16,
                                        wv + 768, wv + 1024, sA, dA, 1);
  gemm_f16<256><<<dim3(mgrid, 2), 256, 0, stream>>>(h_b16, Wt2, h_a16);
  agg_kernel<<<agrid, 256, 0, stream>>>(h_a16, offs, csr, sA, dA, b3, h_b16,
                                        (const float*)nullptr, (const float*)nullptr,
                                        (float*)nullptr, (float*)nullptr, 0);

  pool_kernel<<<dim3(NG, 16), 256, 0, stream>>>(h_b16, batch, pooled);
  fc_kernel<<<NG, 64, 0, stream>>>(pooled, fcW, fcb, (float*)d_out);
}

// Round 14
// 397.593 us; speedup vs baseline: 1.2797x; 1.0930x over previous
//
#include <hip/hip_runtime.h>

#define NN 50000
#define NE 800000
#define D_IN 128
#define D_H 256
#define D_OUT 64
#define NG 64

typedef _Float16 f16;
typedef _Float16 f16x8 __attribute__((ext_vector_type(8)));
typedef _Float16 f16x2 __attribute__((ext_vector_type(2)));
typedef unsigned short u16x8 __attribute__((ext_vector_type(8)));
typedef float f32x4 __attribute__((ext_vector_type(4)));
typedef float f32x2 __attribute__((ext_vector_type(2)));

__device__ __forceinline__ float lrelu(float x){ return x > 0.f ? x : 0.2f*x; }

__device__ __forceinline__ unsigned short f2h(float f){
  f16 h = (f16)f;
  return __builtin_bit_cast(unsigned short, h);
}
__device__ __forceinline__ float h2f(unsigned short b){
  return (float)__builtin_bit_cast(f16, b);
}

// async global->LDS, 16B per lane; lptr is wave-uniform base, lane i lands at base + i*16B
__device__ __forceinline__ void gll16(const unsigned short* g, unsigned short* l){
  __builtin_amdgcn_global_load_lds(
      (const __attribute__((address_space(1))) void*)g,
      (__attribute__((address_space(3))) void*)l,
      16, 0, 0);
}

// acc[0..7] += w * fp8x8 (4x v_cvt_pk_f32_fp8 + 8 fma)
__device__ __forceinline__ void fma8(float* acc, int2 q, float w){
  f32x2 a  = __builtin_amdgcn_cvt_pk_f32_fp8(q.x, false);
  f32x2 b  = __builtin_amdgcn_cvt_pk_f32_fp8(q.x, true);
  f32x2 c2 = __builtin_amdgcn_cvt_pk_f32_fp8(q.y, false);
  f32x2 d2 = __builtin_amdgcn_cvt_pk_f32_fp8(q.y, true);
  acc[0] += w*a[0];  acc[1] += w*a[1];
  acc[2] += w*b[0];  acc[3] += w*b[1];
  acc[4] += w*c2[0]; acc[5] += w*c2[1];
  acc[6] += w*d2[0]; acc[7] += w*d2[1];
}

// ---- W [K][256] -> Wt packed in MFMA B-fragment order ----
__device__ __forceinline__ void cast_one_wt(const float* W, unsigned short* Wt, int K, int idx){
  int k = idx >> 8, n = idx & 255;
  int grp = (n >> 4)*(K >> 5) + (k >> 5);
  int within = ((((k >> 3) & 3) << 4) | (n & 15)) * 8 + (k & 7);
  Wt[grp*512 + within] = f2h(W[idx]);
}

// blocks 0..639: cast W1/W2/W3 | 640..642: wv vectors | 643..838: zero deg | 839..902: zero pooled
__global__ __launch_bounds__(256) void cast_wt_all(const float* __restrict__ W1,
                                                   const float* __restrict__ W2,
                                                   const float* __restrict__ W3,
                                                   const float* __restrict__ as1,
                                                   const float* __restrict__ ad1,
                                                   const float* __restrict__ as2,
                                                   const float* __restrict__ ad2,
                                                   const float* __restrict__ as3,
                                                   const float* __restrict__ ad3,
                                                   unsigned short* __restrict__ Wt0,
                                                   unsigned short* __restrict__ Wt1,
                                                   unsigned short* __restrict__ Wt2,
                                                   float* __restrict__ wv,
                                                   int* __restrict__ deg,
                                                   float* __restrict__ pooled){
  int b = blockIdx.x, t = threadIdx.x;
  if (b < 640){
    int e = b*256 + t;
    if (e < 32768)        cast_one_wt(W1, Wt0, 128, e);
    else if (e < 98304)   cast_one_wt(W2, Wt1, 256, e - 32768);
    else                  cast_one_wt(W3, Wt2, 256, e - 98304);
  } else if (b < 643){
    int L = b - 640;
    const float* W  = (L==0) ? W1 : ((L==1) ? W2 : W3);
    const float* av = (L==0) ? as1 : ((L==1) ? as2 : as3);
    const float* dv = (L==0) ? ad1 : ((L==1) ? ad2 : ad3);
    int K   = (L==0) ? 128 : 256;
    int off = (L==0) ? 0 : ((L==1) ? 256 : 768);
    int k = t;
    if (k < K){
      float ps = 0.f, pd = 0.f;
      for (int n = 0; n < 256; n += 4){
        float4 w  = *(const float4*)(W + k*256 + n);
        float4 a  = *(const float4*)(av + n);
        float4 d2 = *(const float4*)(dv + n);
        ps += w.x*a.x + w.y*a.y + w.z*a.z + w.w*a.w;
        pd += w.x*d2.x + w.y*d2.y + w.z*d2.z + w.w*d2.w;
      }
      wv[off + k]     = ps;
      wv[off + K + k] = pd;
    }
  } else if (b < 839){
    int i = (b - 643)*256 + t;
    if (i < NN) deg[i] = 0;
  } else {
    pooled[(b - 839)*256 + t] = 0.f;
  }
}

// ---- prep: cast x to f16 + s1/d1 + degree count (rank recorded -> atomic-free scatter) ----
__global__ __launch_bounds__(256) void prep_kernel(const float* __restrict__ x,
                                                   unsigned short* __restrict__ xb,
                                                   const float* __restrict__ wv,
                                                   float* __restrict__ s,
                                                   float* __restrict__ d,
                                                   const int* __restrict__ dst,
                                                   int* __restrict__ deg,
                                                   int* __restrict__ erank){
  int gid = blockIdx.x*256 + threadIdx.x;
  if (gid < NN*32){
    float4 v = ((const float4*)x)[gid];
    ushort4 o = { f2h(v.x), f2h(v.y), f2h(v.z), f2h(v.w) };
    ((ushort4*)xb)[gid] = o;
    int node = gid >> 5, sub = gid & 31;
    float4 ws = ((const float4*)wv)[sub];
    float4 wd = ((const float4*)(wv + 128))[sub];
    float ps = v.x*ws.x + v.y*ws.y + v.z*ws.z + v.w*ws.w;
    float pd = v.x*wd.x + v.y*wd.y + v.z*wd.z + v.w*wd.w;
    #pragma unroll
    for (int o2 = 16; o2 > 0; o2 >>= 1){
      ps += __shfl_down(ps, o2, 32);
      pd += __shfl_down(pd, o2, 32);
    }
    if (sub == 0){ s[node] = ps; d[node] = pd; }
  }
  if (gid < NE){
    int r = atomicAdd(&deg[dst[gid]], 1);
    erank[gid] = r;
  }
}

// ---- CSR build ----
__global__ __launch_bounds__(256) void scan_bsum(const int* __restrict__ deg,
                                                 int* __restrict__ bsum){
  __shared__ int sm[256];
  int b = blockIdx.x, t = threadIdx.x;
  int gid = b*256 + t;
  sm[t] = (gid < NN) ? deg[gid] : 0;
  __syncthreads();
  for (int off = 128; off > 0; off >>= 1){
    if (t < off) sm[t] += sm[t+off];
    __syncthreads();
  }
  if (t == 0) bsum[b] = sm[0];
}

__global__ __launch_bounds__(256) void scan_offs(const int* __restrict__ deg,
                                                 const int* __restrict__ bsum,
                                                 int* __restrict__ offs,
                                                 int nblk){
  __shared__ int sb[256];
  __shared__ int sm[256];
  int b = blockIdx.x, t = threadIdx.x;
  sb[t] = (t < nblk) ? bsum[t] : 0;
  __syncthreads();
  for (int off = 1; off < 256; off <<= 1){
    int v = (t >= off) ? sb[t-off] : 0;
    __syncthreads();
    sb[t] += v;
    __syncthreads();
  }
  int base = (b == 0) ? 0 : sb[b-1];
  int gid = b*256 + t;
  int v = (gid < NN) ? deg[gid] : 0;
  sm[t] = v;
  __syncthreads();
  for (int off = 1; off < 256; off <<= 1){
    int u = (t >= off) ? sm[t-off] : 0;
    __syncthreads();
    sm[t] += u;
    __syncthreads();
  }
  int incl = sm[t], excl = incl - v;
  if (gid < NN) offs[gid] = base + excl;
  if (gid == NN-1) offs[NN] = base + incl;
}

// atomic-free scatter: position = offs[dst] + rank (recorded in prep)
__global__ void scatter_csr(const int* __restrict__ src, const int* __restrict__ dst,
                            const int* __restrict__ offs, const int* __restrict__ erank,
                            int* __restrict__ csr_src){
  int e = blockIdx.x*256 + threadIdx.x;
  if (e < NE){
    int dd = dst[e];
    csr_src[offs[dd] + erank[e]] = src[e];
  }
}

// ---- f16 MFMA GEMM: global_load_lds staging + B pipeline; writes f16 C and fp8 C copy ----
template<int K>
__global__ __launch_bounds__(256) void gemm_f16(const unsigned short* __restrict__ A,
                                                const unsigned short* __restrict__ Wt,
                                                unsigned short* __restrict__ C16,
                                                unsigned char* __restrict__ C8){
  constexpr int KS   = 128;          // staged K per pass
  constexpr int NSTG = K / KS;       // 1 or 2
  constexpr int NKS  = K / 32;       // total ksteps
  __shared__ unsigned short As[128*132];   // stage: 128x128; epilogue: 128x132
  const int t = threadIdx.x;
  const int bm = blockIdx.x * 128;
  const int bn = blockIdx.y * 128;
  const int wave = t >> 6, lane = t & 63;
  const int wm = (wave >> 1) * 64, wn = (wave & 1) * 64;
  const int l15 = lane & 15, quad = lane >> 4;

  const int ls = lane & 15;          // staging slot within row
  const int lr = lane >> 4;          // staging row within 4-row group

  const int nb0 = (bn + wn) >> 4;
  #define BPTR(KSI, J) ((const f16x8*)(Wt + ((size_t)((nb0 + (J))*(K>>5) + (KSI)))*512 + lane*8))

  f32x4 acc[4][4];
  #pragma unroll
  for (int i = 0; i < 4; i++)
    #pragma unroll
    for (int j = 0; j < 4; j++){
      f32x4 z = {0.f, 0.f, 0.f, 0.f};
      acc[i][j] = z;
    }

  f16x8 bcur[4];

  #pragma unroll
  for (int stg = 0; stg < NSTG; stg++){
    if (stg > 0) __syncthreads();    // previous MFMA reads must finish before overwrite
    #pragma unroll
    for (int g = 0; g < 8; g++){
      int row = wave*32 + g*4 + lr;
      int gc  = ls ^ (row & 7);
      const unsigned short* gp = A + (size_t)(bm + row)*K + stg*KS + gc*8;
      gll16(gp, &As[(wave*32 + g*4)*128]);
    }
    if (stg == 0){
      #pragma unroll
      for (int j = 0; j < 4; j++) bcur[j] = *BPTR(0, j);
    }
    __syncthreads();
    #pragma unroll
    for (int ksl = 0; ksl < KS/32; ksl++){
      const int ks = stg*(KS/32) + ksl;
      f16x8 bnxt[4];
      if (ks + 1 < NKS){
        #pragma unroll
        for (int j = 0; j < 4; j++) bnxt[j] = *BPTR(ks + 1, j);
      }
      f16x8 af[4];
      const int pc = ((ksl*4 + quad) ^ (l15 & 7)) * 8;
      #pragma unroll
      for (int i = 0; i < 4; i++)
        af[i] = *(const f16x8*)(&As[(wm + i*16 + l15)*128 + pc]);
      #pragma unroll
      for (int j = 0; j < 4; j++)
        #pragma unroll
        for (int i = 0; i < 4; i++)
          acc[i][j] = __builtin_amdgcn_mfma_f32_16x16x32_f16(af[i], bcur[j], acc[i][j], 0, 0, 0);
      if (ks + 1 < NKS){
        #pragma unroll
        for (int j = 0; j < 4; j++) bcur[j] = bnxt[j];
      }
    }
  }
  #undef BPTR

  // epilogue: pack f16 tile into LDS (stride 132), coalesced stores of f16 + fp8 copies
  __syncthreads();
  #pragma unroll
  for (int i = 0; i < 4; i++)
    #pragma unroll
    for (int j = 0; j < 4; j++)
      #pragma unroll
      for (int r = 0; r < 4; r++)
        As[(wm + i*16 + quad*4 + r)*132 + wn + j*16 + l15] = f2h(acc[i][j][r]);
  __syncthreads();
  {
    const int rl = t >> 1, hc = (t & 1)*64;
    const int grow = bm + rl;
    if (grow < NN){
      #pragma unroll
      for (int u = 0; u < 8; u++){
        u16x8 v = *(const u16x8*)(&As[rl*132 + hc + u*8]);
        *(u16x8*)(C16 + (size_t)grow*256 + bn + hc + u*8) = v;
        float f0 = h2f(v[0]), f1 = h2f(v[1]), f2 = h2f(v[2]), f3 = h2f(v[3]);
        float f4 = h2f(v[4]), f5 = h2f(v[5]), f6 = h2f(v[6]), f7 = h2f(v[7]);
        int w0 = __builtin_amdgcn_cvt_pk_fp8_f32(f0, f1, 0, false);
        w0     = __builtin_amdgcn_cvt_pk_fp8_f32(f2, f3, w0, true);
        int w1 = __builtin_amdgcn_cvt_pk_fp8_f32(f4, f5, 0, false);
        w1     = __builtin_amdgcn_cvt_pk_fp8_f32(f6, f7, w1, true);
        int2 pv; pv.x = w0; pv.y = w1;
        *(int2*)(C8 + (size_t)grow*256 + bn + hc + u*8) = pv;
      }
    }
  }
}

// ---- fused softmax + aggregation + next-layer s/d; fp8 gather, f32 accumulate ----
__global__ __launch_bounds__(256) void agg_kernel(const unsigned char* __restrict__ h8p,
                                                  const int* __restrict__ offs,
                                                  const int* __restrict__ csr_src,
                                                  const float* __restrict__ s,
                                                  const float* __restrict__ d,
                                                  const float* __restrict__ bias,
                                                  unsigned short* __restrict__ hout16,
                                                  const float* __restrict__ wv_s,
                                                  const float* __restrict__ wv_d,
                                                  float* __restrict__ s_next,
                                                  float* __restrict__ d_next,
                                                  int do_sd){
  __shared__ int2 meta[4][64];
  const int wvi = threadIdx.x >> 6;
  const int node = blockIdx.x*4 + wvi;
  const int lane = threadIdx.x & 63;
  if (node >= NN) return;
  const float d_i = d[node];
  const int beg = offs[node], end = offs[node+1];
  const int deg = end - beg;

  const int half = lane >> 5;
  const int c    = lane & 31;
  const int2* h8 = (const int2*)h8p;       // row = 32 chunks of 8B (fp8x8)

  float acc[8];
  #pragma unroll
  for (int i = 0; i < 8; i++) acc[i] = 0.f;
  float inv_den;

  if (deg <= 63){
    int sj = 0;
    float e = -1e30f;
    if (lane < deg){
      sj = csr_src[beg + lane];
      e = lrelu(s[sj] + d_i);
    }
    float m = e;
    #pragma unroll
    for (int o = 32; o > 0; o >>= 1) m = fmaxf(m, __shfl_xor(m, o));
    const float e0 = lrelu(s[node] + d_i);
    m = fmaxf(m, e0);

    float w = 0.f;
    if (lane < deg) w = __expf(e - m);
    else if (lane == deg){ w = __expf(e0 - m); sj = node; }
    float den = w;
    #pragma unroll
    for (int o = 32; o > 0; o >>= 1) den += __shfl_xor(den, o);
    inv_den = 1.f / den;

    const int np = (deg + 8) & ~7;          // slots 0..deg (+self), padded; np <= 64
    if (lane < np) meta[wvi][lane] = make_int2(sj, __float_as_int(w));

    for (int eb = 0; eb < np; eb += 8){
      int2 m0 = meta[wvi][eb + half];
      int2 m1 = meta[wvi][eb + 2 + half];
      int2 m2 = meta[wvi][eb + 4 + half];
      int2 m3 = meta[wvi][eb + 6 + half];
      int2 h0 = h8[(size_t)m0.x*32 + c];
      int2 h1 = h8[(size_t)m1.x*32 + c];
      int2 h2 = h8[(size_t)m2.x*32 + c];
      int2 h3 = h8[(size_t)m3.x*32 + c];
      fma8(acc, h0, __int_as_float(m0.y));
      fma8(acc, h1, __int_as_float(m1.y));
      fma8(acc, h2, __int_as_float(m2.y));
      fma8(acc, h3, __int_as_float(m3.y));
    }
  } else {
    // correctness fallback (deg > 63)
    float m_l = -1e30f;
    for (int j = lane; j < deg; j += 64){
      int sj = csr_src[beg + j];
      m_l = fmaxf(m_l, lrelu(s[sj] + d_i));
    }
    #pragma unroll
    for (int o = 32; o > 0; o >>= 1) m_l = fmaxf(m_l, __shfl_xor(m_l, o));
    const float e0 = lrelu(s[node] + d_i);
    const float m = fmaxf(m_l, e0);
    float den_l = (lane == 0) ? __expf(e0 - m) : 0.f;
    for (int j = lane; j < deg; j += 64){
      int sj = csr_src[beg + j];
      den_l += __expf(lrelu(s[sj] + d_i) - m);
    }
    #pragma unroll
    for (int o = 32; o > 0; o >>= 1) den_l += __shfl_xor(den_l, o);
    inv_den = 1.f / den_l;

    if (half == 0){
      fma8(acc, h8[(size_t)node*32 + c], __expf(e0 - m));
    }
    for (int eb = beg; eb < end; eb += 4){
      int e1 = eb + half;
      int e2 = e1 + 2;
      int sa = csr_src[min(e1, end-1)];
      int sb = csr_src[min(e2, end-1)];
      float wa = (e1 < end) ? __expf(lrelu(s[sa] + d_i) - m) : 0.f;
      float wb = (e2 < end) ? __expf(lrelu(s[sb] + d_i) - m) : 0.f;
      fma8(acc, h8[(size_t)sa*32 + c], wa);
      fma8(acc, h8[(size_t)sb*32 + c], wb);
    }
  }

  // normalize, merge halves
  #pragma unroll
  for (int i = 0; i < 8; i++) acc[i] *= inv_den;
  #pragma unroll
  for (int i = 0; i < 8; i++) acc[i] += __shfl_xor(acc[i], 32);

  const float4* bb = (const float4*)(bias + c*8);
  float4 b0 = bb[0], b1 = bb[1];
  acc[0] = fmaxf(acc[0] + b0.x, 0.f); acc[1] = fmaxf(acc[1] + b0.y, 0.f);
  acc[2] = fmaxf(acc[2] + b0.z, 0.f); acc[3] = fmaxf(acc[3] + b0.w, 0.f);
  acc[4] = fmaxf(acc[4] + b1.x, 0.f); acc[5] = fmaxf(acc[5] + b1.y, 0.f);
  acc[6] = fmaxf(acc[6] + b1.z, 0.f); acc[7] = fmaxf(acc[7] + b1.w, 0.f);

  if (half == 0){
    u16x8 o;
    #pragma unroll
    for (int i = 0; i < 8; i++) o[i] = f2h(acc[i]);
    ((u16x8*)hout16)[(size_t)node*32 + c] = o;
  }

  if (do_sd){
    const float4* ws4 = (const float4*)(wv_s + c*8);
    const float4* wd4 = (const float4*)(wv_d + c*8);
    float4 s0 = ws4[0], s1 = ws4[1], dd0 = wd4[0], dd1 = wd4[1];
    float ps = acc[0]*s0.x + acc[1]*s0.y + acc[2]*s0.z + acc[3]*s0.w
             + acc[4]*s1.x + acc[5]*s1.y + acc[6]*s1.z + acc[7]*s1.w;
    float pd = acc[0]*dd0.x + acc[1]*dd0.y + acc[2]*dd0.z + acc[3]*dd0.w
             + acc[4]*dd1.x + acc[5]*dd1.y + acc[6]*dd1.z + acc[7]*dd1.w;
    #pragma unroll
    for (int o = 16; o > 0; o >>= 1){
      ps += __shfl_xor(ps, o);
      pd += __shfl_xor(pd, o);
    }
    if (lane == 0){ s_next[node] = ps; d_next[node] = pd; }
  }
}

// ---- global add pool (batch sorted), f16 input: 1024 blocks ----
__device__ __forceinline__ int lbound(const int* a, int n, int v){
  int lo = 0, hi = n;
  while (lo < hi){ int mid = (lo + hi) >> 1; if (a[mid] < v) lo = mid + 1; else hi = mid; }
  return lo;
}

__global__ __launch_bounds__(256) void pool_kernel(const unsigned short* __restrict__ h16,
                                                   const int* __restrict__ batch,
                                                   float* __restrict__ pooled){
  int g = blockIdx.x, split = blockIdx.y, t = threadIdx.x;
  int lo = lbound(batch, NN, g);
  int hi = lbound(batch, NN, g + 1);
  int len = hi - lo;
  int chunk = (len + 15) >> 4;
  int b  = lo + split*chunk;
  int e2 = min(hi, b + chunk);
  float acc = 0.f;
  for (int i = b; i < e2; i++) acc += h2f(h16[(size_t)i*D_H + t]);
  atomicAdd(&pooled[g*D_H + t], acc);
}

// ---- final FC ----
__global__ __launch_bounds__(64) void fc_kernel(const float* __restrict__ pooled,
                                                const float* __restrict__ fcW,
                                                const float* __restrict__ fcb,
                                                float* __restrict__ out){
  int g = blockIdx.x, o = threadIdx.x;
  float acc = fcb[o];
  for (int k = 0; k < D_H; k++) acc += pooled[g*D_H + k] * fcW[k*D_OUT + o];
  out[g*D_OUT + o] = acc;
}

extern "C" void kernel_launch(void* const* d_in, const int* in_sizes, int n_in,
                              void* d_out, int out_size, void* d_ws, size_t ws_size,
                              hipStream_t stream){
  const float* x     = (const float*)d_in[0];
  const int*   ei    = (const int*)d_in[1];
  const int*   batch = (const int*)d_in[2];
  const float* W1  = (const float*)d_in[3];
  const float* as1 = (const float*)d_in[4];
  const float* ad1 = (const float*)d_in[5];
  const float* b1  = (const float*)d_in[6];
  const float* W2  = (const float*)d_in[7];
  const float* as2 = (const float*)d_in[8];
  const float* ad2 = (const float*)d_in[9];
  const float* b2  = (const float*)d_in[10];
  const float* W3  = (const float*)d_in[11];
  const float* as3 = (const float*)d_in[12];
  const float* ad3 = (const float*)d_in[13];
  const float* b3  = (const float*)d_in[14];
  const float* fcW = (const float*)d_in[15];
  const float* fcb = (const float*)d_in[16];

  const int* src = ei;
  const int* dst = ei + NE;

  char* p = (char*)d_ws;
  auto alloc = [&](size_t bytes) -> void* {
    void* r = (void*)p;
    p += (bytes + 255) & ~(size_t)255;
    return r;
  };
  unsigned short* h_a16 = (unsigned short*)alloc((size_t)NN*D_H*2);
  unsigned short* h_b16 = (unsigned short*)alloc((size_t)NN*D_H*2);
  unsigned char*  h_a8  = (unsigned char*)alloc((size_t)NN*D_H);
  unsigned short* xb    = (unsigned short*)alloc((size_t)NN*D_IN*2);
  unsigned short* Wt0   = (unsigned short*)alloc((size_t)256*D_IN*2);
  unsigned short* Wt1   = (unsigned short*)alloc((size_t)256*256*2);
  unsigned short* Wt2   = (unsigned short*)alloc((size_t)256*256*2);
  float* sA     = (float*)alloc((size_t)NN*4);
  float* dA     = (float*)alloc((size_t)NN*4);
  float* sB     = (float*)alloc((size_t)NN*4);
  float* dB     = (float*)alloc((size_t)NN*4);
  float* wv     = (float*)alloc((size_t)1280*4);
  int* deg      = (int*)alloc((size_t)NN*4);
  int* offs     = (int*)alloc((size_t)(NN+1)*4);
  int* erank    = (int*)alloc((size_t)NE*4);
  int* bsum     = (int*)alloc((size_t)256*4);
  int* csr      = (int*)alloc((size_t)NE*4);
  float* pooled = (float*)alloc((size_t)NG*D_H*4);

  const int nblk = (NN + 255)/256;   // 196

  cast_wt_all<<<903, 256, 0, stream>>>(W1, W2, W3, as1, ad1, as2, ad2, as3, ad3,
                                       Wt0, Wt1, Wt2, wv, deg, pooled);
  prep_kernel<<<(NN*32 + 255)/256, 256, 0, stream>>>(x, xb, wv, sA, dA, dst, deg, erank);
  scan_bsum<<<nblk, 256, 0, stream>>>(deg, bsum);
  scan_offs<<<nblk, 256, 0, stream>>>(deg, bsum, offs, nblk);
  scatter_csr<<<(NE + 255)/256, 256, 0, stream>>>(src, dst, offs, erank, csr);

  const int mgrid = (NN + 127)/128;
  const int agrid = (NN + 3)/4;

  gemm_f16<128><<<dim3(mgrid, 2), 256, 0, stream>>>(xb, Wt0, h_a16, h_a8);
  agg_kernel<<<agrid, 256, 0, stream>>>(h_a8, offs, csr, sA, dA, b1, h_b16,
                                        wv + 256, wv + 512, sB, dB, 1);
  gemm_f16<256><<<dim3(mgrid, 2), 256, 0, stream>>>(h_b16, Wt1, h_a16, h_a8);
  agg_kernel<<<agrid, 256, 0, stream>>>(h_a8, offs, csr, sB, dB, b2, h_b16,
                                        wv + 768, wv + 1024, sA, dA, 1);
  gemm_f16<256><<<dim3(mgrid, 2), 256, 0, stream>>>(h_b16, Wt2, h_a16, h_a8);
  agg_kernel<<<agrid, 256, 0, stream>>>(h_a8, offs, csr, sA, dA, b3, h_b16,
                                        (const float*)nullptr, (const float*)nullptr,
                                        (float*)nullptr, (float*)nullptr, 0);

  pool_kernel<<<dim3(NG, 16), 256, 0, stream>>>(h_b16, batch, pooled);
  fc_kernel<<<NG, 64, 0, stream>>>(pooled, fcW, fcb, (float*)d_out);
}

// Round 15
// 371.901 us; speedup vs baseline: 1.3681x; 1.0691x over previous
//
#include <hip/hip_runtime.h>

#define NN 50000
#define NE 800000
#define D_IN 128
#define D_H 256
#define D_OUT 64
#define NG 64

typedef _Float16 f16;
typedef _Float16 f16x8 __attribute__((ext_vector_type(8)));
typedef _Float16 f16x2 __attribute__((ext_vector_type(2)));
typedef unsigned short u16x8 __attribute__((ext_vector_type(8)));
typedef float f32x4 __attribute__((ext_vector_type(4)));
typedef float f32x2 __attribute__((ext_vector_type(2)));

__device__ __forceinline__ float lrelu(float x){ return x > 0.f ? x : 0.2f*x; }

__device__ __forceinline__ unsigned short f2h(float f){
  f16 h = (f16)f;
  return __builtin_bit_cast(unsigned short, h);
}
__device__ __forceinline__ float h2f(unsigned short b){
  return (float)__builtin_bit_cast(f16, b);
}

// async global->LDS, 16B per lane; lptr is wave-uniform base, lane i lands at base + i*16B
__device__ __forceinline__ void gll16(const unsigned short* g, unsigned short* l){
  __builtin_amdgcn_global_load_lds(
      (const __attribute__((address_space(1))) void*)g,
      (__attribute__((address_space(3))) void*)l,
      16, 0, 0);
}

// acc[0..7] += w * fp8x8 (4x v_cvt_pk_f32_fp8 + 8 fma)
__device__ __forceinline__ void fma8(float* acc, int2 q, float w){
  f32x2 a  = __builtin_amdgcn_cvt_pk_f32_fp8(q.x, false);
  f32x2 b  = __builtin_amdgcn_cvt_pk_f32_fp8(q.x, true);
  f32x2 c2 = __builtin_amdgcn_cvt_pk_f32_fp8(q.y, false);
  f32x2 d2 = __builtin_amdgcn_cvt_pk_f32_fp8(q.y, true);
  acc[0] += w*a[0];  acc[1] += w*a[1];
  acc[2] += w*b[0];  acc[3] += w*b[1];
  acc[4] += w*c2[0]; acc[5] += w*c2[1];
  acc[6] += w*d2[0]; acc[7] += w*d2[1];
}

// ---- W [K][256] -> Wt packed in MFMA B-fragment order ----
__device__ __forceinline__ void cast_one_wt(const float* W, unsigned short* Wt, int K, int idx){
  int k = idx >> 8, n = idx & 255;
  int grp = (n >> 4)*(K >> 5) + (k >> 5);
  int within = ((((k >> 3) & 3) << 4) | (n & 15)) * 8 + (k & 7);
  Wt[grp*512 + within] = f2h(W[idx]);
}

// blocks 0..639: cast W1/W2/W3 | 640..642: wv vectors | 643..838: zero deg | 839..902: zero pooled
__global__ __launch_bounds__(256) void cast_wt_all(const float* __restrict__ W1,
                                                   const float* __restrict__ W2,
                                                   const float* __restrict__ W3,
                                                   const float* __restrict__ as1,
                                                   const float* __restrict__ ad1,
                                                   const float* __restrict__ as2,
                                                   const float* __restrict__ ad2,
                                                   const float* __restrict__ as3,
                                                   const float* __restrict__ ad3,
                                                   unsigned short* __restrict__ Wt0,
                                                   unsigned short* __restrict__ Wt1,
                                                   unsigned short* __restrict__ Wt2,
                                                   float* __restrict__ wv,
                                                   int* __restrict__ deg,
                                                   float* __restrict__ pooled){
  int b = blockIdx.x, t = threadIdx.x;
  if (b < 640){
    int e = b*256 + t;
    if (e < 32768)        cast_one_wt(W1, Wt0, 128, e);
    else if (e < 98304)   cast_one_wt(W2, Wt1, 256, e - 32768);
    else                  cast_one_wt(W3, Wt2, 256, e - 98304);
  } else if (b < 643){
    int L = b - 640;
    const float* W  = (L==0) ? W1 : ((L==1) ? W2 : W3);
    const float* av = (L==0) ? as1 : ((L==1) ? as2 : as3);
    const float* dv = (L==0) ? ad1 : ((L==1) ? ad2 : ad3);
    int K   = (L==0) ? 128 : 256;
    int off = (L==0) ? 0 : ((L==1) ? 256 : 768);
    int k = t;
    if (k < K){
      float ps = 0.f, pd = 0.f;
      for (int n = 0; n < 256; n += 4){
        float4 w  = *(const float4*)(W + k*256 + n);
        float4 a  = *(const float4*)(av + n);
        float4 d2 = *(const float4*)(dv + n);
        ps += w.x*a.x + w.y*a.y + w.z*a.z + w.w*a.w;
        pd += w.x*d2.x + w.y*d2.y + w.z*d2.z + w.w*d2.w;
      }
      wv[off + k]     = ps;
      wv[off + K + k] = pd;
    }
  } else if (b < 839){
    int i = (b - 643)*256 + t;
    if (i < NN) deg[i] = 0;
  } else {
    pooled[(b - 839)*256 + t] = 0.f;
  }
}

// ---- prep: cast x to f16 + s1/d1 + degree count (rank recorded -> atomic-free scatter) ----
__global__ __launch_bounds__(256) void prep_kernel(const float* __restrict__ x,
                                                   unsigned short* __restrict__ xb,
                                                   const float* __restrict__ wv,
                                                   float* __restrict__ s,
                                                   float* __restrict__ d,
                                                   const int* __restrict__ dst,
                                                   int* __restrict__ deg,
                                                   int* __restrict__ erank){
  int gid = blockIdx.x*256 + threadIdx.x;
  if (gid < NN*32){
    float4 v = ((const float4*)x)[gid];
    ushort4 o = { f2h(v.x), f2h(v.y), f2h(v.z), f2h(v.w) };
    ((ushort4*)xb)[gid] = o;
    int node = gid >> 5, sub = gid & 31;
    float4 ws = ((const float4*)wv)[sub];
    float4 wd = ((const float4*)(wv + 128))[sub];
    float ps = v.x*ws.x + v.y*ws.y + v.z*ws.z + v.w*ws.w;
    float pd = v.x*wd.x + v.y*wd.y + v.z*wd.z + v.w*wd.w;
    #pragma unroll
    for (int o2 = 16; o2 > 0; o2 >>= 1){
      ps += __shfl_down(ps, o2, 32);
      pd += __shfl_down(pd, o2, 32);
    }
    if (sub == 0){ s[node] = ps; d[node] = pd; }
  }
  if (gid < NE){
    int r = atomicAdd(&deg[dst[gid]], 1);
    erank[gid] = r;
  }
}

// ---- CSR build ----
__global__ __launch_bounds__(256) void scan_bsum(const int* __restrict__ deg,
                                                 int* __restrict__ bsum){
  __shared__ int sm[256];
  int b = blockIdx.x, t = threadIdx.x;
  int gid = b*256 + t;
  sm[t] = (gid < NN) ? deg[gid] : 0;
  __syncthreads();
  for (int off = 128; off > 0; off >>= 1){
    if (t < off) sm[t] += sm[t+off];
    __syncthreads();
  }
  if (t == 0) bsum[b] = sm[0];
}

__global__ __launch_bounds__(256) void scan_offs(const int* __restrict__ deg,
                                                 const int* __restrict__ bsum,
                                                 int* __restrict__ offs,
                                                 int nblk){
  __shared__ int sb[256];
  __shared__ int sm[256];
  int b = blockIdx.x, t = threadIdx.x;
  sb[t] = (t < nblk) ? bsum[t] : 0;
  __syncthreads();
  for (int off = 1; off < 256; off <<= 1){
    int v = (t >= off) ? sb[t-off] : 0;
    __syncthreads();
    sb[t] += v;
    __syncthreads();
  }
  int base = (b == 0) ? 0 : sb[b-1];
  int gid = b*256 + t;
  int v = (gid < NN) ? deg[gid] : 0;
  sm[t] = v;
  __syncthreads();
  for (int off = 1; off < 256; off <<= 1){
    int u = (t >= off) ? sm[t-off] : 0;
    __syncthreads();
    sm[t] += u;
    __syncthreads();
  }
  int incl = sm[t], excl = incl - v;
  if (gid < NN) offs[gid] = base + excl;
  if (gid == NN-1) offs[NN] = base + incl;
}

// atomic-free scatter: position = offs[dst] + rank (recorded in prep)
__global__ void scatter_csr(const int* __restrict__ src, const int* __restrict__ dst,
                            const int* __restrict__ offs, const int* __restrict__ erank,
                            int* __restrict__ csr_src){
  int e = blockIdx.x*256 + threadIdx.x;
  if (e < NE){
    int dd = dst[e];
    csr_src[offs[dd] + erank[e]] = src[e];
  }
}

// ---- f16 MFMA GEMM: global_load_lds staging + B pipeline; writes fp8 C only ----
template<int K>
__global__ __launch_bounds__(256) void gemm_f16(const unsigned short* __restrict__ A,
                                                const unsigned short* __restrict__ Wt,
                                                unsigned char* __restrict__ C8){
  constexpr int KS   = 128;          // staged K per pass
  constexpr int NSTG = K / KS;       // 1 or 2
  constexpr int NKS  = K / 32;       // total ksteps
  __shared__ unsigned short As[128*132];   // stage: 128x128; epilogue: 128x132
  const int t = threadIdx.x;
  const int bm = blockIdx.x * 128;
  const int bn = blockIdx.y * 128;
  const int wave = t >> 6, lane = t & 63;
  const int wm = (wave >> 1) * 64, wn = (wave & 1) * 64;
  const int l15 = lane & 15, quad = lane >> 4;

  const int ls = lane & 15;          // staging slot within row
  const int lr = lane >> 4;          // staging row within 4-row group

  const int nb0 = (bn + wn) >> 4;
  #define BPTR(KSI, J) ((const f16x8*)(Wt + ((size_t)((nb0 + (J))*(K>>5) + (KSI)))*512 + lane*8))

  f32x4 acc[4][4];
  #pragma unroll
  for (int i = 0; i < 4; i++)
    #pragma unroll
    for (int j = 0; j < 4; j++){
      f32x4 z = {0.f, 0.f, 0.f, 0.f};
      acc[i][j] = z;
    }

  f16x8 bcur[4];

  #pragma unroll
  for (int stg = 0; stg < NSTG; stg++){
    if (stg > 0) __syncthreads();    // previous MFMA reads must finish before overwrite
    #pragma unroll
    for (int g = 0; g < 8; g++){
      int row = wave*32 + g*4 + lr;
      int gc  = ls ^ (row & 7);
      const unsigned short* gp = A + (size_t)(bm + row)*K + stg*KS + gc*8;
      gll16(gp, &As[(wave*32 + g*4)*128]);
    }
    if (stg == 0){
      #pragma unroll
      for (int j = 0; j < 4; j++) bcur[j] = *BPTR(0, j);
    }
    __syncthreads();
    #pragma unroll
    for (int ksl = 0; ksl < KS/32; ksl++){
      const int ks = stg*(KS/32) + ksl;
      f16x8 bnxt[4];
      if (ks + 1 < NKS){
        #pragma unroll
        for (int j = 0; j < 4; j++) bnxt[j] = *BPTR(ks + 1, j);
      }
      f16x8 af[4];
      const int pc = ((ksl*4 + quad) ^ (l15 & 7)) * 8;
      #pragma unroll
      for (int i = 0; i < 4; i++)
        af[i] = *(const f16x8*)(&As[(wm + i*16 + l15)*128 + pc]);
      #pragma unroll
      for (int j = 0; j < 4; j++)
        #pragma unroll
        for (int i = 0; i < 4; i++)
          acc[i][j] = __builtin_amdgcn_mfma_f32_16x16x32_f16(af[i], bcur[j], acc[i][j], 0, 0, 0);
      if (ks + 1 < NKS){
        #pragma unroll
        for (int j = 0; j < 4; j++) bcur[j] = bnxt[j];
      }
    }
  }
  #undef BPTR

  // epilogue: pack f16 tile into LDS (stride 132), coalesced fp8 stores
  __syncthreads();
  #pragma unroll
  for (int i = 0; i < 4; i++)
    #pragma unroll
    for (int j = 0; j < 4; j++)
      #pragma unroll
      for (int r = 0; r < 4; r++)
        As[(wm + i*16 + quad*4 + r)*132 + wn + j*16 + l15] = f2h(acc[i][j][r]);
  __syncthreads();
  {
    const int rl = t >> 1, hc = (t & 1)*64;
    const int grow = bm + rl;
    if (grow < NN){
      #pragma unroll
      for (int u = 0; u < 8; u++){
        u16x8 v = *(const u16x8*)(&As[rl*132 + hc + u*8]);
        float f0 = h2f(v[0]), f1 = h2f(v[1]), f2 = h2f(v[2]), f3 = h2f(v[3]);
        float f4 = h2f(v[4]), f5 = h2f(v[5]), f6 = h2f(v[6]), f7 = h2f(v[7]);
        int w0 = __builtin_amdgcn_cvt_pk_fp8_f32(f0, f1, 0, false);
        w0     = __builtin_amdgcn_cvt_pk_fp8_f32(f2, f3, w0, true);
        int w1 = __builtin_amdgcn_cvt_pk_fp8_f32(f4, f5, 0, false);
        w1     = __builtin_amdgcn_cvt_pk_fp8_f32(f6, f7, w1, true);
        int2 pv; pv.x = w0; pv.y = w1;
        *(int2*)(C8 + (size_t)grow*256 + bn + hc + u*8) = pv;
      }
    }
  }
}

// ---- fused softmax + aggregation + next-layer s/d; fp8 gather, f32 accumulate ----
__global__ __launch_bounds__(256) void agg_kernel(const unsigned char* __restrict__ h8p,
                                                  const int* __restrict__ offs,
                                                  const int* __restrict__ csr_src,
                                                  const float* __restrict__ s,
                                                  const float* __restrict__ d,
                                                  const float* __restrict__ bias,
                                                  unsigned short* __restrict__ hout16,
                                                  const float* __restrict__ wv_s,
                                                  const float* __restrict__ wv_d,
                                                  float* __restrict__ s_next,
                                                  float* __restrict__ d_next,
                                                  int do_sd){
  __shared__ int2 meta[4][64];
  const int wvi = threadIdx.x >> 6;
  const int node = blockIdx.x*4 + wvi;
  const int lane = threadIdx.x & 63;
  if (node >= NN) return;
  const float d_i = d[node];
  const int beg = offs[node], end = offs[node+1];
  const int deg = end - beg;

  const int half = lane >> 5;
  const int c    = lane & 31;
  const int2* h8 = (const int2*)h8p;       // row = 32 chunks of 8B (fp8x8)

  float acc[8];
  #pragma unroll
  for (int i = 0; i < 8; i++) acc[i] = 0.f;
  float inv_den;

  if (deg <= 63){
    int sj = 0;
    float e = -1e30f;
    if (lane < deg){
      sj = csr_src[beg + lane];
      e = lrelu(s[sj] + d_i);
    }
    float m = e;
    #pragma unroll
    for (int o = 32; o > 0; o >>= 1) m = fmaxf(m, __shfl_xor(m, o));
    const float e0 = lrelu(s[node] + d_i);
    m = fmaxf(m, e0);

    float w = 0.f;
    if (lane < deg) w = __expf(e - m);
    else if (lane == deg){ w = __expf(e0 - m); sj = node; }
    float den = w;
    #pragma unroll
    for (int o = 32; o > 0; o >>= 1) den += __shfl_xor(den, o);
    inv_den = 1.f / den;

    const int np = (deg + 8) & ~7;          // slots 0..deg (+self), padded; np <= 64
    if (lane < np) meta[wvi][lane] = make_int2(sj, __float_as_int(w));

    for (int eb = 0; eb < np; eb += 8){
      int2 m0 = meta[wvi][eb + half];
      int2 m1 = meta[wvi][eb + 2 + half];
      int2 m2 = meta[wvi][eb + 4 + half];
      int2 m3 = meta[wvi][eb + 6 + half];
      int2 h0 = h8[(size_t)m0.x*32 + c];
      int2 h1 = h8[(size_t)m1.x*32 + c];
      int2 h2 = h8[(size_t)m2.x*32 + c];
      int2 h3 = h8[(size_t)m3.x*32 + c];
      fma8(acc, h0, __int_as_float(m0.y));
      fma8(acc, h1, __int_as_float(m1.y));
      fma8(acc, h2, __int_as_float(m2.y));
      fma8(acc, h3, __int_as_float(m3.y));
    }
  } else {
    // correctness fallback (deg > 63)
    float m_l = -1e30f;
    for (int j = lane; j < deg; j += 64){
      int sj = csr_src[beg + j];
      m_l = fmaxf(m_l, lrelu(s[sj] + d_i));
    }
    #pragma unroll
    for (int o = 32; o > 0; o >>= 1) m_l = fmaxf(m_l, __shfl_xor(m_l, o));
    const float e0 = lrelu(s[node] + d_i);
    const float m = fmaxf(m_l, e0);
    float den_l = (lane == 0) ? __expf(e0 - m) : 0.f;
    for (int j = lane; j < deg; j += 64){
      int sj = csr_src[beg + j];
      den_l += __expf(lrelu(s[sj] + d_i) - m);
    }
    #pragma unroll
    for (int o = 32; o > 0; o >>= 1) den_l += __shfl_xor(den_l, o);
    inv_den = 1.f / den_l;

    if (half == 0){
      fma8(acc, h8[(size_t)node*32 + c], __expf(e0 - m));
    }
    for (int eb = beg; eb < end; eb += 4){
      int e1 = eb + half;
      int e2 = e1 + 2;
      int sa = csr_src[min(e1, end-1)];
      int sb = csr_src[min(e2, end-1)];
      float wa = (e1 < end) ? __expf(lrelu(s[sa] + d_i) - m) : 0.f;
      float wb = (e2 < end) ? __expf(lrelu(s[sb] + d_i) - m) : 0.f;
      fma8(acc, h8[(size_t)sa*32 + c], wa);
      fma8(acc, h8[(size_t)sb*32 + c], wb);
    }
  }

  // normalize, merge halves
  #pragma unroll
  for (int i = 0; i < 8; i++) acc[i] *= inv_den;
  #pragma unroll
  for (int i = 0; i < 8; i++) acc[i] += __shfl_xor(acc[i], 32);

  const float4* bb = (const float4*)(bias + c*8);
  float4 b0 = bb[0], b1 = bb[1];
  acc[0] = fmaxf(acc[0] + b0.x, 0.f); acc[1] = fmaxf(acc[1] + b0.y, 0.f);
  acc[2] = fmaxf(acc[2] + b0.z, 0.f); acc[3] = fmaxf(acc[3] + b0.w, 0.f);
  acc[4] = fmaxf(acc[4] + b1.x, 0.f); acc[5] = fmaxf(acc[5] + b1.y, 0.f);
  acc[6] = fmaxf(acc[6] + b1.z, 0.f); acc[7] = fmaxf(acc[7] + b1.w, 0.f);

  if (half == 0){
    u16x8 o;
    #pragma unroll
    for (int i = 0; i < 8; i++) o[i] = f2h(acc[i]);
    ((u16x8*)hout16)[(size_t)node*32 + c] = o;
  }

  if (do_sd){
    const float4* ws4 = (const float4*)(wv_s + c*8);
    const float4* wd4 = (const float4*)(wv_d + c*8);
    float4 s0 = ws4[0], s1 = ws4[1], dd0 = wd4[0], dd1 = wd4[1];
    float ps = acc[0]*s0.x + acc[1]*s0.y + acc[2]*s0.z + acc[3]*s0.w
             + acc[4]*s1.x + acc[5]*s1.y + acc[6]*s1.z + acc[7]*s1.w;
    float pd = acc[0]*dd0.x + acc[1]*dd0.y + acc[2]*dd0.z + acc[3]*dd0.w
             + acc[4]*dd1.x + acc[5]*dd1.y + acc[6]*dd1.z + acc[7]*dd1.w;
    #pragma unroll
    for (int o = 16; o > 0; o >>= 1){
      ps += __shfl_xor(ps, o);
      pd += __shfl_xor(pd, o);
    }
    if (lane == 0){ s_next[node] = ps; d_next[node] = pd; }
  }
}

// ---- global add pool (batch sorted), f16 input: 1024 blocks ----
__device__ __forceinline__ int lbound(const int* a, int n, int v){
  int lo = 0, hi = n;
  while (lo < hi){ int mid = (lo + hi) >> 1; if (a[mid] < v) lo = mid + 1; else hi = mid; }
  return lo;
}

__global__ __launch_bounds__(256) void pool_kernel(const unsigned short* __restrict__ h16,
                                                   const int* __restrict__ batch,
                                                   float* __restrict__ pooled){
  int g = blockIdx.x, split = blockIdx.y, t = threadIdx.x;
  int lo = lbound(batch, NN, g);
  int hi = lbound(batch, NN, g + 1);
  int len = hi - lo;
  int chunk = (len + 15) >> 4;
  int b  = lo + split*chunk;
  int e2 = min(hi, b + chunk);
  float acc = 0.f;
  for (int i = b; i < e2; i++) acc += h2f(h16[(size_t)i*D_H + t]);
  atomicAdd(&pooled[g*D_H + t], acc);
}

// ---- final FC ----
__global__ __launch_bounds__(64) void fc_kernel(const float* __restrict__ pooled,
                                                const float* __restrict__ fcW,
                                                const float* __restrict__ fcb,
                                                float* __restrict__ out){
  int g = blockIdx.x, o = threadIdx.x;
  float acc = fcb[o];
  for (int k = 0; k < D_H; k++) acc += pooled[g*D_H + k] * fcW[k*D_OUT + o];
  out[g*D_OUT + o] = acc;
}

extern "C" void kernel_launch(void* const* d_in, const int* in_sizes, int n_in,
                              void* d_out, int out_size, void* d_ws, size_t ws_size,
                              hipStream_t stream){
  const float* x     = (const float*)d_in[0];
  const int*   ei    = (const int*)d_in[1];
  const int*   batch = (const int*)d_in[2];
  const float* W1  = (const float*)d_in[3];
  const float* as1 = (const float*)d_in[4];
  const float* ad1 = (const float*)d_in[5];
  const float* b1  = (const float*)d_in[6];
  const float* W2  = (const float*)d_in[7];
  const float* as2 = (const float*)d_in[8];
  const float* ad2 = (const float*)d_in[9];
  const float* b2  = (const float*)d_in[10];
  const float* W3  = (const float*)d_in[11];
  const float* as3 = (const float*)d_in[12];
  const float* ad3 = (const float*)d_in[13];
  const float* b3  = (const float*)d_in[14];
  const float* fcW = (const float*)d_in[15];
  const float* fcb = (const float*)d_in[16];

  const int* src = ei;
  const int* dst = ei + NE;

  char* p = (char*)d_ws;
  auto alloc = [&](size_t bytes) -> void* {
    void* r = (void*)p;
    p += (bytes + 255) & ~(size_t)255;
    return r;
  };
  unsigned short* h_b16 = (unsigned short*)alloc((size_t)NN*D_H*2);
  unsigned char*  h_a8  = (unsigned char*)alloc((size_t)NN*D_H);
  unsigned short* xb    = (unsigned short*)alloc((size_t)NN*D_IN*2);
  unsigned short* Wt0   = (unsigned short*)alloc((size_t)256*D_IN*2);
  unsigned short* Wt1   = (unsigned short*)alloc((size_t)256*256*2);
  unsigned short* Wt2   = (unsigned short*)alloc((size_t)256*256*2);
  float* sA     = (float*)alloc((size_t)NN*4);
  float* dA     = (float*)alloc((size_t)NN*4);
  float* sB     = (float*)alloc((size_t)NN*4);
  float* dB     = (float*)alloc((size_t)NN*4);
  float* wv     = (float*)alloc((size_t)1280*4);
  int* deg      = (int*)alloc((size_t)NN*4);
  int* offs     = (int*)alloc((size_t)(NN+1)*4);
  int* erank    = (int*)alloc((size_t)NE*4);
  int* bsum     = (int*)alloc((size_t)256*4);
  int* csr      = (int*)alloc((size_t)NE*4);
  float* pooled = (float*)alloc((size_t)NG*D_H*4);

  const int nblk = (NN + 255)/256;   // 196

  cast_wt_all<<<903, 256, 0, stream>>>(W1, W2, W3, as1, ad1, as2, ad2, as3, ad3,
                                       Wt0, Wt1, Wt2, wv, deg, pooled);
  prep_kernel<<<(NN*32 + 255)/256, 256, 0, stream>>>(x, xb, wv, sA, dA, dst, deg, erank);
  scan_bsum<<<nblk, 256, 0, stream>>>(deg, bsum);
  scan_offs<<<nblk, 256, 0, stream>>>(deg, bsum, offs, nblk);
  scatter_csr<<<(NE + 255)/256, 256, 0, stream>>>(src, dst, offs, erank, csr);

  const int mgrid = (NN + 127)/128;
  const int agrid = (NN + 3)/4;

  gemm_f16<128><<<dim3(mgrid, 2), 256, 0, stream>>>(xb, Wt0, h_a8);
  agg_kernel<<<agrid, 256, 0, stream>>>(h_a8, offs, csr, sA, dA, b1, h_b16,
                                        wv + 256, wv + 512, sB, dB, 1);
  gemm_f16<256><<<dim3(mgrid, 2), 256, 0, stream>>>(h_b16, Wt1, h_a8);
  agg_kernel<<<agrid, 256, 0, stream>>>(h_a8, offs, csr, sB, dB, b2, h_b16,
                                        wv + 768, wv + 1024, sA, dA, 1);
  gemm_f16<256><<<dim3(mgrid, 2), 256, 0, stream>>>(h_b16, Wt2, h_a8);
  agg_kernel<<<agrid, 256, 0, stream>>>(h_a8, offs, csr, sA, dA, b3, h_b16,
                                        (const float*)nullptr, (const float*)nullptr,
                                        (float*)nullptr, (float*)nullptr, 0);

  pool_kernel<<<dim3(NG, 16), 256, 0, stream>>>(h_b16, batch, pooled);
  fc_kernel<<<NG, 64, 0, stream>>>(pooled, fcW, fcb, (float*)d_out);
}